// Round 1
// baseline (486.742 us; speedup 1.0000x reference)
//
#include <hip/hip_runtime.h>
#include <hip/hip_bf16.h>

#define Bn 256
#define Tn 256
#define Cn 384
#define Hn 6
#define HSn 64

typedef __attribute__((ext_vector_type(8))) __bf16 bf16x8;
typedef __attribute__((ext_vector_type(4))) float f32x4;

// XOR swizzle in ELEMENT units for bf16 LDS tiles whose row stride is a
// multiple of 64 elements (128B): spreads 8 consecutive rows across 8
// distinct 16B slots -> 2-way max bank aliasing (free) on ds_read_b128.
__device__ __forceinline__ int swz(int row, int col) {
  return col ^ ((row & 7) << 3);
}

__device__ __forceinline__ bf16x8 load_cvt8(const float* src) {
  f32x4 f0 = *(const f32x4*)(src);
  f32x4 f1 = *(const f32x4*)(src + 4);
  bf16x8 t;
  t[0] = (__bf16)f0[0]; t[1] = (__bf16)f0[1];
  t[2] = (__bf16)f0[2]; t[3] = (__bf16)f0[3];
  t[4] = (__bf16)f1[0]; t[5] = (__bf16)f1[1];
  t[6] = (__bf16)f1[2]; t[7] = (__bf16)f1[3];
  return t;
}

// ---------------------------------------------------------------------------
// Kernel 1: fused QKV projection + causal flash attention for one (b, h).
// Block = 256 threads (4 waves); wave w owns token rows [64w, 64w+64).
// ---------------------------------------------------------------------------
__global__ __launch_bounds__(256, 1)
void attn_fused(const float* __restrict__ x, const float* __restrict__ Wk,
                const float* __restrict__ Wq, const float* __restrict__ Wv,
                __bf16* __restrict__ att) {
  __shared__ __bf16 Ks[Tn * HSn];     // [key][d]   swizzled
  __shared__ __bf16 Vt[HSn * Tn];     // [d][key]   swizzled
  __shared__ __bf16 Pq[4][64 * 64];   // per-wave scratch [row][col] swizzled

  // XCD-grouping swizzle: all 6 heads of a batch b land on the same XCD
  // (consecutive-by-8 physical blocks share an XCD on MI355X).
  int p = blockIdx.x;
  int r = p & 7;
  int q2 = p >> 3;
  int slot = q2 / Hn;
  int h = q2 - slot * Hn;
  int b = r + 8 * slot;

  int tid = threadIdx.x;
  int w = tid >> 6;
  int l = tid & 63;
  int l16 = l & 15;
  int l4 = l >> 4;

  const float* xb = x + (size_t)b * Tn * Cn;
  int qr = w * 64;  // wave's token-row base

  f32x4 aq[4][4], ak[4][4], av[4][4];
#pragma unroll
  for (int i = 0; i < 4; ++i)
#pragma unroll
    for (int j = 0; j < 4; ++j) {
      aq[i][j] = (f32x4){0.f, 0.f, 0.f, 0.f};
      ak[i][j] = (f32x4){0.f, 0.f, 0.f, 0.f};
      av[i][j] = (f32x4){0.f, 0.f, 0.f, 0.f};
    }

  // ---- QKV projections: out[t,d] = sum_c x[t,c] * W[d,c] -----------------
  for (int ct6 = 0; ct6 < 6; ++ct6) {
    int c0 = ct6 * 64;
    bf16x8 a[4][2];
#pragma unroll
    for (int rt = 0; rt < 4; ++rt)
#pragma unroll
      for (int kk = 0; kk < 2; ++kk)
        a[rt][kk] =
            load_cvt8(xb + (size_t)(qr + rt * 16 + l16) * Cn + c0 + kk * 32 + l4 * 8);

    auto doMat = [&](const float* W, f32x4 (&acc)[4][4]) {
#pragma unroll
      for (int ct = 0; ct < 4; ++ct)
#pragma unroll
        for (int kk = 0; kk < 2; ++kk) {
          bf16x8 bb = load_cvt8(W + (size_t)(h * 64 + ct * 16 + l16) * Cn + c0 +
                                kk * 32 + l4 * 8);
#pragma unroll
          for (int rt = 0; rt < 4; ++rt)
            acc[rt][ct] = __builtin_amdgcn_mfma_f32_16x16x32_bf16(
                a[rt][kk], bb, acc[rt][ct], 0, 0, 0);
        }
    };
    doMat(Wq, aq);
    doMat(Wk, ak);
    doMat(Wv, av);
  }

  // ---- write K, V^T to LDS; Q (pre-scaled) to per-wave scratch -----------
#pragma unroll
  for (int rt = 0; rt < 4; ++rt)
#pragma unroll
    for (int ct = 0; ct < 4; ++ct)
#pragma unroll
      for (int rr = 0; rr < 4; ++rr) {
        int trow = qr + rt * 16 + l4 * 4 + rr;  // token index 0..255
        int col = ct * 16 + l16;                // d index 0..63
        Ks[trow * HSn + swz(trow, col)] = (__bf16)ak[rt][ct][rr];
        Vt[col * Tn + swz(col, trow)] = (__bf16)av[rt][ct][rr];
        int lrow = rt * 16 + l4 * 4 + rr;       // local q row 0..63
        Pq[w][lrow * 64 + swz(lrow, col)] = (__bf16)(aq[rt][ct][rr] * 0.125f);
      }
  __syncthreads();

  // ---- load Q A-fragments back (C-layout -> A-layout via LDS) ------------
  bf16x8 qa[4][2];
#pragma unroll
  for (int rt = 0; rt < 4; ++rt)
#pragma unroll
    for (int kk = 0; kk < 2; ++kk) {
      int row = rt * 16 + l16;
      qa[rt][kk] = *(const bf16x8*)&Pq[w][row * 64 + swz(row, kk * 32 + l4 * 8)];
    }

  // ---- flash attention over key tiles jt = 0..w --------------------------
  const float LOG2E = 1.44269504088896f;
  f32x4 o[4][4];
  f32x4 m_[4], lsum[4];
#pragma unroll
  for (int i = 0; i < 4; ++i) {
#pragma unroll
    for (int j = 0; j < 4; ++j) o[i][j] = (f32x4){0.f, 0.f, 0.f, 0.f};
    m_[i] = (f32x4){-1e30f, -1e30f, -1e30f, -1e30f};
    lsum[i] = (f32x4){0.f, 0.f, 0.f, 0.f};
  }

  for (int jt = 0; jt <= w; ++jt) {
    f32x4 s[4][4];
#pragma unroll
    for (int i = 0; i < 4; ++i)
#pragma unroll
      for (int j = 0; j < 4; ++j) s[i][j] = (f32x4){0.f, 0.f, 0.f, 0.f};

    // S = Q K^T   (scale already folded into Q)
#pragma unroll
    for (int kk = 0; kk < 2; ++kk)
#pragma unroll
      for (int ct = 0; ct < 4; ++ct) {
        int key = jt * 64 + ct * 16 + l16;
        bf16x8 kb = *(const bf16x8*)&Ks[key * HSn + swz(key, kk * 32 + l4 * 8)];
#pragma unroll
        for (int rt = 0; rt < 4; ++rt)
          s[rt][ct] = __builtin_amdgcn_mfma_f32_16x16x32_bf16(qa[rt][kk], kb,
                                                              s[rt][ct], 0, 0, 0);
      }

    // causal mask on the diagonal tile
    if (jt == w) {
#pragma unroll
      for (int rt = 0; rt < 4; ++rt)
#pragma unroll
        for (int ct = 0; ct < 4; ++ct)
#pragma unroll
          for (int rr = 0; rr < 4; ++rr) {
            int ql = rt * 16 + l4 * 4 + rr;
            int kl = ct * 16 + l16;
            if (kl > ql) s[rt][ct][rr] = -1e30f;
          }
    }

    // online softmax update (rows live in 16-lane groups)
#pragma unroll
    for (int rt = 0; rt < 4; ++rt) {
      float mt[4], corr[4], rsum[4];
#pragma unroll
      for (int rr = 0; rr < 4; ++rr)
        mt[rr] = fmaxf(fmaxf(s[rt][0][rr], s[rt][1][rr]),
                       fmaxf(s[rt][2][rr], s[rt][3][rr]));
#pragma unroll
      for (int off = 1; off < 16; off <<= 1)
#pragma unroll
        for (int rr = 0; rr < 4; ++rr)
          mt[rr] = fmaxf(mt[rr], __shfl_xor(mt[rr], off, 64));
#pragma unroll
      for (int rr = 0; rr < 4; ++rr) {
        float mnew = fmaxf(m_[rt][rr], mt[rr]);
        corr[rr] = exp2f((m_[rt][rr] - mnew) * LOG2E);
        m_[rt][rr] = mnew;
      }
#pragma unroll
      for (int ct = 0; ct < 4; ++ct)
#pragma unroll
        for (int rr = 0; rr < 4; ++rr)
          s[rt][ct][rr] = exp2f((s[rt][ct][rr] - m_[rt][rr]) * LOG2E);
#pragma unroll
      for (int rr = 0; rr < 4; ++rr)
        rsum[rr] = (s[rt][0][rr] + s[rt][1][rr]) + (s[rt][2][rr] + s[rt][3][rr]);
#pragma unroll
      for (int off = 1; off < 16; off <<= 1)
#pragma unroll
        for (int rr = 0; rr < 4; ++rr) rsum[rr] += __shfl_xor(rsum[rr], off, 64);
#pragma unroll
      for (int rr = 0; rr < 4; ++rr)
        lsum[rt][rr] = lsum[rt][rr] * corr[rr] + rsum[rr];
#pragma unroll
      for (int cd = 0; cd < 4; ++cd)
#pragma unroll
        for (int rr = 0; rr < 4; ++rr) o[rt][cd][rr] *= corr[rr];

      // write P tile (bf16) to per-wave scratch for the PV MFMA
#pragma unroll
      for (int ct = 0; ct < 4; ++ct)
#pragma unroll
        for (int rr = 0; rr < 4; ++rr) {
          int lr = rt * 16 + l4 * 4 + rr;
          Pq[w][lr * 64 + swz(lr, ct * 16 + l16)] = (__bf16)s[rt][ct][rr];
        }
    }

    // O += P V
#pragma unroll
    for (int kk = 0; kk < 2; ++kk) {
      bf16x8 pa[4];
#pragma unroll
      for (int rt = 0; rt < 4; ++rt) {
        int row = rt * 16 + l16;
        pa[rt] = *(const bf16x8*)&Pq[w][row * 64 + swz(row, kk * 32 + l4 * 8)];
      }
#pragma unroll
      for (int cd = 0; cd < 4; ++cd) {
        int drow = cd * 16 + l16;
        bf16x8 vb =
            *(const bf16x8*)&Vt[drow * Tn + swz(drow, jt * 64 + kk * 32 + l4 * 8)];
#pragma unroll
        for (int rt = 0; rt < 4; ++rt)
          o[rt][cd] = __builtin_amdgcn_mfma_f32_16x16x32_bf16(pa[rt], vb,
                                                              o[rt][cd], 0, 0, 0);
      }
    }
  }

  // ---- normalize and write att (bf16) to workspace -----------------------
  __bf16* ab = att + (size_t)b * Tn * Cn + h * HSn;
#pragma unroll
  for (int rt = 0; rt < 4; ++rt)
#pragma unroll
    for (int cd = 0; cd < 4; ++cd)
#pragma unroll
      for (int rr = 0; rr < 4; ++rr) {
        int trow = qr + rt * 16 + l4 * 4 + rr;
        float val = o[rt][cd][rr] / lsum[rt][rr];
        ab[(size_t)trow * Cn + cd * 16 + l16] = (__bf16)val;
      }
}

// ---------------------------------------------------------------------------
// Kernel 2: out = att @ Wp^T + bp    (M=65536, N=384, K=384), f32 output.
// 128x128 tiles, 256 threads (2x2 waves of 64x64).
// ---------------------------------------------------------------------------
__global__ __launch_bounds__(256, 2)
void proj_kernel(const __bf16* __restrict__ att, const float* __restrict__ Wp,
                 const float* __restrict__ bp, float* __restrict__ out) {
  __shared__ __bf16 As[128 * 64];
  __shared__ __bf16 Bs[128 * 64];

  // bn-major order: consecutive blocks share Wp panel, stream att once.
  int bn = blockIdx.x / 512;
  int bm = blockIdx.x - bn * 512;
  int m0 = bm * 128, n0 = bn * 128;

  int tid = threadIdx.x;
  int l = tid & 63;
  int wid = tid >> 6;
  int wr = wid >> 1, wc = wid & 1;
  int l16 = l & 15, l4 = l >> 4;

  f32x4 acc[4][4];
#pragma unroll
  for (int i = 0; i < 4; ++i)
#pragma unroll
    for (int j = 0; j < 4; ++j) acc[i][j] = (f32x4){0.f, 0.f, 0.f, 0.f};

  for (int kt = 0; kt < 6; ++kt) {
    int k0 = kt * 64;
    // stage A (att, already bf16): 128x64 tile
#pragma unroll
    for (int i = 0; i < 4; ++i) {
      int chunk = tid + 256 * i;  // 0..1023 chunks of 8 elements
      int row = chunk >> 3;
      int c8 = (chunk & 7) * 8;
      bf16x8 v = *(const bf16x8*)&att[(size_t)(m0 + row) * Cn + k0 + c8];
      *(bf16x8*)&As[row * 64 + swz(row, c8)] = v;
    }
    // stage B (Wp f32 -> bf16): rows are output dims n
#pragma unroll
    for (int i = 0; i < 4; ++i) {
      int chunk = tid + 256 * i;
      int row = chunk >> 3;
      int c8 = (chunk & 7) * 8;
      bf16x8 t = load_cvt8(Wp + (size_t)(n0 + row) * Cn + k0 + c8);
      *(bf16x8*)&Bs[row * 64 + swz(row, c8)] = t;
    }
    __syncthreads();
#pragma unroll
    for (int kk = 0; kk < 2; ++kk) {
      bf16x8 a[4], bb[4];
#pragma unroll
      for (int rt = 0; rt < 4; ++rt) {
        int row = wr * 64 + rt * 16 + l16;
        a[rt] = *(const bf16x8*)&As[row * 64 + swz(row, kk * 32 + l4 * 8)];
      }
#pragma unroll
      for (int ct = 0; ct < 4; ++ct) {
        int row = wc * 64 + ct * 16 + l16;
        bb[ct] = *(const bf16x8*)&Bs[row * 64 + swz(row, kk * 32 + l4 * 8)];
      }
#pragma unroll
      for (int rt = 0; rt < 4; ++rt)
#pragma unroll
        for (int ct = 0; ct < 4; ++ct)
          acc[rt][ct] = __builtin_amdgcn_mfma_f32_16x16x32_bf16(a[rt], bb[ct],
                                                                acc[rt][ct], 0, 0, 0);
    }
    __syncthreads();
  }

  // epilogue: += bias, f32 store
#pragma unroll
  for (int ct = 0; ct < 4; ++ct) {
    int n = n0 + wc * 64 + ct * 16 + l16;
    float bias = bp[n];
#pragma unroll
    for (int rt = 0; rt < 4; ++rt)
#pragma unroll
      for (int rr = 0; rr < 4; ++rr) {
        int m = m0 + wr * 64 + rt * 16 + l4 * 4 + rr;
        out[(size_t)m * Cn + n] = acc[rt][ct][rr] + bias;
      }
  }
}

extern "C" void kernel_launch(void* const* d_in, const int* in_sizes, int n_in,
                              void* d_out, int out_size, void* d_ws, size_t ws_size,
                              hipStream_t stream) {
  const float* x  = (const float*)d_in[0];
  const float* Wk = (const float*)d_in[1];
  const float* Wq = (const float*)d_in[2];
  const float* Wv = (const float*)d_in[3];
  const float* Wp = (const float*)d_in[4];
  const float* bp = (const float*)d_in[5];
  float* out = (float*)d_out;
  __bf16* att = (__bf16*)d_ws;  // B*T*C bf16 = 48 MB scratch

  attn_fused<<<Bn * Hn, 256, 0, stream>>>(x, Wk, Wq, Wv, att);
  proj_kernel<<<512 * 3, 256, 0, stream>>>(att, Wp, bp, out);
}

// Round 2
// 338.554 us; speedup vs baseline: 1.4377x; 1.4377x over previous
//
#include <hip/hip_runtime.h>
#include <hip/hip_bf16.h>

#define Bn 256
#define Tn 256
#define Cn 384
#define Hn 6
#define HSn 64

typedef __attribute__((ext_vector_type(8))) __bf16 bf16x8;
typedef __attribute__((ext_vector_type(4))) float f32x4;

// XOR swizzle in ELEMENT units for bf16 LDS tiles with 64-elem (128B) rows.
__device__ __forceinline__ int swz(int row, int col) {
  return col ^ ((row & 7) << 3);
}

__device__ __forceinline__ bf16x8 load_cvt8(const float* src) {
  f32x4 f0 = *(const f32x4*)(src);
  f32x4 f1 = *(const f32x4*)(src + 4);
  bf16x8 t;
  t[0] = (__bf16)f0[0]; t[1] = (__bf16)f0[1];
  t[2] = (__bf16)f0[2]; t[3] = (__bf16)f0[3];
  t[4] = (__bf16)f1[0]; t[5] = (__bf16)f1[1];
  t[6] = (__bf16)f1[2]; t[7] = (__bf16)f1[3];
  return t;
}

// ---------------------------------------------------------------------------
// K1: QKV projection GEMM. M=65536 (b*t), N=1152 (q|k|v x h*d), K=384.
// 128x128 tiles, 256 thr. Grid m-major (9 n-blocks consecutive) + XCD chunk
// swizzle -> x-tile L2-resident across its 9 n-blocks. Q pre-scaled 0.125.
// V written transposed [b,h,d,t] via LDS-transpose epilogue.
// ---------------------------------------------------------------------------
__global__ __launch_bounds__(256, 2)
void qkv_gemm(const float* __restrict__ x, const float* __restrict__ Wq,
              const float* __restrict__ Wk, const float* __restrict__ Wv,
              __bf16* __restrict__ qb, __bf16* __restrict__ kb,
              __bf16* __restrict__ vt) {
  __shared__ __bf16 smem[128 * 128];   // As[128*64] | Bs[128*64]; reused as Tr
  __bf16* As = smem;
  __bf16* Bs = smem + 128 * 64;

  int p = blockIdx.x;
  int wgid = (p & 7) * 576 + (p >> 3);   // 4608 blocks, bijective (4608%8==0)
  int bm = wgid / 9, bn = wgid % 9;
  int m0 = bm * 128;
  const float* W = (bn < 3) ? Wq : (bn < 6) ? Wk : Wv;
  int wrow0 = (bn % 3) * 128;

  int tid = threadIdx.x;
  int l = tid & 63, wid = tid >> 6;
  int wr = wid >> 1, wc = wid & 1;
  int l16 = l & 15, l4 = l >> 4;

  f32x4 acc[4][4];
#pragma unroll
  for (int i = 0; i < 4; ++i)
#pragma unroll
    for (int j = 0; j < 4; ++j) acc[i][j] = (f32x4){0.f, 0.f, 0.f, 0.f};

  for (int kt = 0; kt < 6; ++kt) {
    int k0 = kt * 64;
#pragma unroll
    for (int i = 0; i < 4; ++i) {
      int chunk = tid + 256 * i;
      int row = chunk >> 3;
      int c8 = (chunk & 7) * 8;
      *(bf16x8*)&As[row * 64 + swz(row, c8)] =
          load_cvt8(x + (size_t)(m0 + row) * Cn + k0 + c8);
      *(bf16x8*)&Bs[row * 64 + swz(row, c8)] =
          load_cvt8(W + (size_t)(wrow0 + row) * Cn + k0 + c8);
    }
    __syncthreads();
#pragma unroll
    for (int kk = 0; kk < 2; ++kk) {
      bf16x8 a[4], bb[4];
#pragma unroll
      for (int rt = 0; rt < 4; ++rt) {
        int row = wr * 64 + rt * 16 + l16;
        a[rt] = *(const bf16x8*)&As[row * 64 + swz(row, kk * 32 + l4 * 8)];
      }
#pragma unroll
      for (int ct = 0; ct < 4; ++ct) {
        int row = wc * 64 + ct * 16 + l16;
        bb[ct] = *(const bf16x8*)&Bs[row * 64 + swz(row, kk * 32 + l4 * 8)];
      }
#pragma unroll
      for (int rt = 0; rt < 4; ++rt)
#pragma unroll
        for (int ct = 0; ct < 4; ++ct)
          acc[rt][ct] = __builtin_amdgcn_mfma_f32_16x16x32_bf16(a[rt], bb[ct],
                                                                acc[rt][ct], 0, 0, 0);
    }
    __syncthreads();
  }

  int b = bm >> 1;             // 128 rows never cross a batch (256-row, aligned)
  int t0 = (bm & 1) * 128;

  if (bn < 6) {
    float scale = (bn < 3) ? 0.125f : 1.0f;
    __bf16* ob = (bn < 3) ? qb : kb;
    int nbase = (bn % 3) * 128;
#pragma unroll
    for (int ct = 0; ct < 4; ++ct) {
      int nn = nbase + wc * 64 + ct * 16 + l16;
      int h = nn >> 6, d = nn & 63;
      __bf16* dst = ob + (((size_t)b * Hn + h) * Tn) * HSn + d;
#pragma unroll
      for (int rt = 0; rt < 4; ++rt)
#pragma unroll
        for (int rr = 0; rr < 4; ++rr) {
          int t = t0 + wr * 64 + rt * 16 + l4 * 4 + rr;
          dst[(size_t)t * HSn] = (__bf16)(acc[rt][ct][rr] * scale);
        }
    }
  } else {
    // V: transpose 128(m) x 128(n) tile through LDS, store [b,h,d,t].
#pragma unroll
    for (int ct = 0; ct < 4; ++ct)
#pragma unroll
      for (int rt = 0; rt < 4; ++rt)
#pragma unroll
        for (int rr = 0; rr < 4; ++rr) {
          int nl = wc * 64 + ct * 16 + l16;
          int ml = wr * 64 + rt * 16 + l4 * 4 + rr;
          smem[nl * 128 + (ml ^ ((nl & 7) << 3))] = (__bf16)acc[rt][ct][rr];
        }
    __syncthreads();
    int nl = tid >> 1;
    int mh = (tid & 1) * 64;
    int vcol = (bn - 6) * 128 + nl;
    int h = vcol >> 6, d = vcol & 63;
    __bf16* dst = vt + (((size_t)b * Hn + h) * HSn + d) * Tn + t0 + mh;
#pragma unroll
    for (int c8 = 0; c8 < 8; ++c8) {
      bf16x8 v = *(const bf16x8*)&smem[nl * 128 + ((mh + c8 * 8) ^ ((nl & 7) << 3))];
      *(bf16x8*)&dst[c8 * 8] = v;
    }
  }
}

// ---------------------------------------------------------------------------
// K2: flash attention from precomputed Q (scaled), K [b,h,t,d], V^T [b,h,d,t].
// Block = 256 thr = 4 waves x 32 q-rows; one (b, h, 128-row q-tile) per block.
// LDS only for per-wave P relayout (16 KB) -> multi-block/CU occupancy.
// ---------------------------------------------------------------------------
__global__ __launch_bounds__(256, 3)
void attn2(const __bf16* __restrict__ qb, const __bf16* __restrict__ kb,
           const __bf16* __restrict__ vt, __bf16* __restrict__ att) {
  __shared__ __bf16 Pq[4][32 * 64];

  int p = blockIdx.x;
  int wgid = (p & 7) * 384 + (p >> 3);   // 3072 blocks
  int b = wgid / 12;
  int r = wgid % 12;
  int h = r >> 1, qt = r & 1;

  int tid = threadIdx.x, w = tid >> 6, l = tid & 63;
  int l16 = l & 15, l4 = l >> 4;

  size_t bh = (size_t)b * Hn + h;
  const __bf16* Q = qb + bh * Tn * HSn;
  const __bf16* K = kb + bh * Tn * HSn;
  const __bf16* V = vt + bh * HSn * Tn;

  int q0 = qt * 128 + w * 32;

  bf16x8 qa[2][2];
#pragma unroll
  for (int rt = 0; rt < 2; ++rt)
#pragma unroll
    for (int kk = 0; kk < 2; ++kk)
      qa[rt][kk] =
          *(const bf16x8*)&Q[(size_t)(q0 + rt * 16 + l16) * HSn + kk * 32 + l4 * 8];

  const float LOG2E = 1.44269504088896f;
  f32x4 o[2][4];
  f32x4 m_[2], lsum[2];
#pragma unroll
  for (int i = 0; i < 2; ++i) {
#pragma unroll
    for (int j = 0; j < 4; ++j) o[i][j] = (f32x4){0.f, 0.f, 0.f, 0.f};
    m_[i] = (f32x4){-1e30f, -1e30f, -1e30f, -1e30f};
    lsum[i] = (f32x4){0.f, 0.f, 0.f, 0.f};
  }

  int nt = q0 / 64 + 1;
  for (int jt = 0; jt < nt; ++jt) {
    f32x4 s[2][4];
#pragma unroll
    for (int i = 0; i < 2; ++i)
#pragma unroll
      for (int j = 0; j < 4; ++j) s[i][j] = (f32x4){0.f, 0.f, 0.f, 0.f};

#pragma unroll
    for (int kk = 0; kk < 2; ++kk)
#pragma unroll
      for (int ct = 0; ct < 4; ++ct) {
        bf16x8 kf = *(const bf16x8*)&K[(size_t)(jt * 64 + ct * 16 + l16) * HSn +
                                       kk * 32 + l4 * 8];
#pragma unroll
        for (int rt = 0; rt < 2; ++rt)
          s[rt][ct] = __builtin_amdgcn_mfma_f32_16x16x32_bf16(qa[rt][kk], kf,
                                                              s[rt][ct], 0, 0, 0);
      }

    if (jt == nt - 1) {
#pragma unroll
      for (int rt = 0; rt < 2; ++rt)
#pragma unroll
        for (int ct = 0; ct < 4; ++ct)
#pragma unroll
          for (int rr = 0; rr < 4; ++rr) {
            int ql = q0 + rt * 16 + l4 * 4 + rr;
            int kl = jt * 64 + ct * 16 + l16;
            if (kl > ql) s[rt][ct][rr] = -1e30f;
          }
    }

#pragma unroll
    for (int rt = 0; rt < 2; ++rt) {
      float mt[4], corr[4], rsum[4];
#pragma unroll
      for (int rr = 0; rr < 4; ++rr)
        mt[rr] = fmaxf(fmaxf(s[rt][0][rr], s[rt][1][rr]),
                       fmaxf(s[rt][2][rr], s[rt][3][rr]));
#pragma unroll
      for (int off = 1; off < 16; off <<= 1)
#pragma unroll
        for (int rr = 0; rr < 4; ++rr)
          mt[rr] = fmaxf(mt[rr], __shfl_xor(mt[rr], off, 64));
#pragma unroll
      for (int rr = 0; rr < 4; ++rr) {
        float mnew = fmaxf(m_[rt][rr], mt[rr]);
        corr[rr] = exp2f((m_[rt][rr] - mnew) * LOG2E);
        m_[rt][rr] = mnew;
      }
#pragma unroll
      for (int ct = 0; ct < 4; ++ct)
#pragma unroll
        for (int rr = 0; rr < 4; ++rr)
          s[rt][ct][rr] = exp2f((s[rt][ct][rr] - m_[rt][rr]) * LOG2E);
#pragma unroll
      for (int rr = 0; rr < 4; ++rr)
        rsum[rr] = (s[rt][0][rr] + s[rt][1][rr]) + (s[rt][2][rr] + s[rt][3][rr]);
#pragma unroll
      for (int off = 1; off < 16; off <<= 1)
#pragma unroll
        for (int rr = 0; rr < 4; ++rr) rsum[rr] += __shfl_xor(rsum[rr], off, 64);
#pragma unroll
      for (int rr = 0; rr < 4; ++rr)
        lsum[rt][rr] = lsum[rt][rr] * corr[rr] + rsum[rr];
#pragma unroll
      for (int cd = 0; cd < 4; ++cd)
#pragma unroll
        for (int rr = 0; rr < 4; ++rr) o[rt][cd][rr] *= corr[rr];
#pragma unroll
      for (int ct = 0; ct < 4; ++ct)
#pragma unroll
        for (int rr = 0; rr < 4; ++rr) {
          int lr = rt * 16 + l4 * 4 + rr;
          Pq[w][lr * 64 + swz(lr, ct * 16 + l16)] = (__bf16)s[rt][ct][rr];
        }
    }

#pragma unroll
    for (int kk = 0; kk < 2; ++kk) {
      bf16x8 pa[2];
#pragma unroll
      for (int rt = 0; rt < 2; ++rt) {
        int row = rt * 16 + l16;
        pa[rt] = *(const bf16x8*)&Pq[w][row * 64 + swz(row, kk * 32 + l4 * 8)];
      }
#pragma unroll
      for (int cd = 0; cd < 4; ++cd) {
        bf16x8 vf = *(const bf16x8*)&V[(size_t)(cd * 16 + l16) * Tn + jt * 64 +
                                       kk * 32 + l4 * 8];
#pragma unroll
        for (int rt = 0; rt < 2; ++rt)
          o[rt][cd] = __builtin_amdgcn_mfma_f32_16x16x32_bf16(pa[rt], vf,
                                                              o[rt][cd], 0, 0, 0);
      }
    }
  }

#pragma unroll
  for (int rt = 0; rt < 2; ++rt)
#pragma unroll
    for (int cd = 0; cd < 4; ++cd)
#pragma unroll
      for (int rr = 0; rr < 4; ++rr) {
        int t = q0 + rt * 16 + l4 * 4 + rr;
        float val = o[rt][cd][rr] / lsum[rt][rr];
        att[((size_t)b * Tn + t) * Cn + h * HSn + cd * 16 + l16] = (__bf16)val;
      }
}

// ---------------------------------------------------------------------------
// Fallback K (ws too small): fused QKV + attention per (b,h). Known-good.
// ---------------------------------------------------------------------------
__global__ __launch_bounds__(256, 1)
void attn_fused(const float* __restrict__ x, const float* __restrict__ Wk,
                const float* __restrict__ Wq, const float* __restrict__ Wv,
                __bf16* __restrict__ att) {
  __shared__ __bf16 Ks[Tn * HSn];
  __shared__ __bf16 Vt[HSn * Tn];
  __shared__ __bf16 Pq[4][64 * 64];

  int p = blockIdx.x;
  int r = p & 7;
  int q2 = p >> 3;
  int slot = q2 / Hn;
  int h = q2 - slot * Hn;
  int b = r + 8 * slot;

  int tid = threadIdx.x;
  int w = tid >> 6;
  int l = tid & 63;
  int l16 = l & 15;
  int l4 = l >> 4;

  const float* xb = x + (size_t)b * Tn * Cn;
  int qr = w * 64;

  f32x4 aq[4][4], ak[4][4], av[4][4];
#pragma unroll
  for (int i = 0; i < 4; ++i)
#pragma unroll
    for (int j = 0; j < 4; ++j) {
      aq[i][j] = (f32x4){0.f, 0.f, 0.f, 0.f};
      ak[i][j] = (f32x4){0.f, 0.f, 0.f, 0.f};
      av[i][j] = (f32x4){0.f, 0.f, 0.f, 0.f};
    }

  for (int ct6 = 0; ct6 < 6; ++ct6) {
    int c0 = ct6 * 64;
    bf16x8 a[4][2];
#pragma unroll
    for (int rt = 0; rt < 4; ++rt)
#pragma unroll
      for (int kk = 0; kk < 2; ++kk)
        a[rt][kk] =
            load_cvt8(xb + (size_t)(qr + rt * 16 + l16) * Cn + c0 + kk * 32 + l4 * 8);

    auto doMat = [&](const float* W, f32x4 (&acc)[4][4]) {
#pragma unroll
      for (int ct = 0; ct < 4; ++ct)
#pragma unroll
        for (int kk = 0; kk < 2; ++kk) {
          bf16x8 bb = load_cvt8(W + (size_t)(h * 64 + ct * 16 + l16) * Cn + c0 +
                                kk * 32 + l4 * 8);
#pragma unroll
          for (int rt = 0; rt < 4; ++rt)
            acc[rt][ct] = __builtin_amdgcn_mfma_f32_16x16x32_bf16(
                a[rt][kk], bb, acc[rt][ct], 0, 0, 0);
        }
    };
    doMat(Wq, aq);
    doMat(Wk, ak);
    doMat(Wv, av);
  }

#pragma unroll
  for (int rt = 0; rt < 4; ++rt)
#pragma unroll
    for (int ct = 0; ct < 4; ++ct)
#pragma unroll
      for (int rr = 0; rr < 4; ++rr) {
        int trow = qr + rt * 16 + l4 * 4 + rr;
        int col = ct * 16 + l16;
        Ks[trow * HSn + swz(trow, col)] = (__bf16)ak[rt][ct][rr];
        Vt[col * Tn + swz(col, trow)] = (__bf16)av[rt][ct][rr];
        int lrow = rt * 16 + l4 * 4 + rr;
        Pq[w][lrow * 64 + swz(lrow, col)] = (__bf16)(aq[rt][ct][rr] * 0.125f);
      }
  __syncthreads();

  bf16x8 qa[4][2];
#pragma unroll
  for (int rt = 0; rt < 4; ++rt)
#pragma unroll
    for (int kk = 0; kk < 2; ++kk) {
      int row = rt * 16 + l16;
      qa[rt][kk] = *(const bf16x8*)&Pq[w][row * 64 + swz(row, kk * 32 + l4 * 8)];
    }

  const float LOG2E = 1.44269504088896f;
  f32x4 o[4][4];
  f32x4 m_[4], lsum[4];
#pragma unroll
  for (int i = 0; i < 4; ++i) {
#pragma unroll
    for (int j = 0; j < 4; ++j) o[i][j] = (f32x4){0.f, 0.f, 0.f, 0.f};
    m_[i] = (f32x4){-1e30f, -1e30f, -1e30f, -1e30f};
    lsum[i] = (f32x4){0.f, 0.f, 0.f, 0.f};
  }

  for (int jt = 0; jt <= w; ++jt) {
    f32x4 s[4][4];
#pragma unroll
    for (int i = 0; i < 4; ++i)
#pragma unroll
      for (int j = 0; j < 4; ++j) s[i][j] = (f32x4){0.f, 0.f, 0.f, 0.f};

#pragma unroll
    for (int kk = 0; kk < 2; ++kk)
#pragma unroll
      for (int ct = 0; ct < 4; ++ct) {
        int key = jt * 64 + ct * 16 + l16;
        bf16x8 kf = *(const bf16x8*)&Ks[key * HSn + swz(key, kk * 32 + l4 * 8)];
#pragma unroll
        for (int rt = 0; rt < 4; ++rt)
          s[rt][ct] = __builtin_amdgcn_mfma_f32_16x16x32_bf16(qa[rt][kk], kf,
                                                              s[rt][ct], 0, 0, 0);
      }

    if (jt == w) {
#pragma unroll
      for (int rt = 0; rt < 4; ++rt)
#pragma unroll
        for (int ct = 0; ct < 4; ++ct)
#pragma unroll
          for (int rr = 0; rr < 4; ++rr) {
            int ql = rt * 16 + l4 * 4 + rr;
            int kl = ct * 16 + l16;
            if (kl > ql) s[rt][ct][rr] = -1e30f;
          }
    }

#pragma unroll
    for (int rt = 0; rt < 4; ++rt) {
      float mt[4], corr[4], rsum[4];
#pragma unroll
      for (int rr = 0; rr < 4; ++rr)
        mt[rr] = fmaxf(fmaxf(s[rt][0][rr], s[rt][1][rr]),
                       fmaxf(s[rt][2][rr], s[rt][3][rr]));
#pragma unroll
      for (int off = 1; off < 16; off <<= 1)
#pragma unroll
        for (int rr = 0; rr < 4; ++rr)
          mt[rr] = fmaxf(mt[rr], __shfl_xor(mt[rr], off, 64));
#pragma unroll
      for (int rr = 0; rr < 4; ++rr) {
        float mnew = fmaxf(m_[rt][rr], mt[rr]);
        corr[rr] = exp2f((m_[rt][rr] - mnew) * LOG2E);
        m_[rt][rr] = mnew;
      }
#pragma unroll
      for (int ct = 0; ct < 4; ++ct)
#pragma unroll
        for (int rr = 0; rr < 4; ++rr)
          s[rt][ct][rr] = exp2f((s[rt][ct][rr] - m_[rt][rr]) * LOG2E);
#pragma unroll
      for (int rr = 0; rr < 4; ++rr)
        rsum[rr] = (s[rt][0][rr] + s[rt][1][rr]) + (s[rt][2][rr] + s[rt][3][rr]);
#pragma unroll
      for (int off = 1; off < 16; off <<= 1)
#pragma unroll
        for (int rr = 0; rr < 4; ++rr) rsum[rr] += __shfl_xor(rsum[rr], off, 64);
#pragma unroll
      for (int rr = 0; rr < 4; ++rr)
        lsum[rt][rr] = lsum[rt][rr] * corr[rr] + rsum[rr];
#pragma unroll
      for (int cd = 0; cd < 4; ++cd)
#pragma unroll
        for (int rr = 0; rr < 4; ++rr) o[rt][cd][rr] *= corr[rr];

#pragma unroll
      for (int ct = 0; ct < 4; ++ct)
#pragma unroll
        for (int rr = 0; rr < 4; ++rr) {
          int lr = rt * 16 + l4 * 4 + rr;
          Pq[w][lr * 64 + swz(lr, ct * 16 + l16)] = (__bf16)s[rt][ct][rr];
        }
    }

#pragma unroll
    for (int kk = 0; kk < 2; ++kk) {
      bf16x8 pa[4];
#pragma unroll
      for (int rt = 0; rt < 4; ++rt) {
        int row = rt * 16 + l16;
        pa[rt] = *(const bf16x8*)&Pq[w][row * 64 + swz(row, kk * 32 + l4 * 8)];
      }
#pragma unroll
      for (int cd = 0; cd < 4; ++cd) {
        int drow = cd * 16 + l16;
        bf16x8 vb =
            *(const bf16x8*)&Vt[drow * Tn + swz(drow, jt * 64 + kk * 32 + l4 * 8)];
#pragma unroll
        for (int rt = 0; rt < 4; ++rt)
          o[rt][cd] = __builtin_amdgcn_mfma_f32_16x16x32_bf16(pa[rt], vb,
                                                              o[rt][cd], 0, 0, 0);
      }
    }
  }

  __bf16* ab = att + (size_t)b * Tn * Cn + h * HSn;
#pragma unroll
  for (int rt = 0; rt < 4; ++rt)
#pragma unroll
    for (int cd = 0; cd < 4; ++cd)
#pragma unroll
      for (int rr = 0; rr < 4; ++rr) {
        int trow = qr + rt * 16 + l4 * 4 + rr;
        float val = o[rt][cd][rr] / lsum[rt][rr];
        ab[(size_t)trow * Cn + cd * 16 + l16] = (__bf16)val;
      }
}

// ---------------------------------------------------------------------------
// K3: out = att @ Wp^T + bp    (M=65536, N=384, K=384), f32 output.
// ---------------------------------------------------------------------------
__global__ __launch_bounds__(256, 2)
void proj_kernel(const __bf16* __restrict__ att, const float* __restrict__ Wp,
                 const float* __restrict__ bp, float* __restrict__ out) {
  __shared__ __bf16 As[128 * 64];
  __shared__ __bf16 Bs[128 * 64];

  int bn = blockIdx.x / 512;
  int bm = blockIdx.x - bn * 512;
  int m0 = bm * 128, n0 = bn * 128;

  int tid = threadIdx.x;
  int l = tid & 63;
  int wid = tid >> 6;
  int wr = wid >> 1, wc = wid & 1;
  int l16 = l & 15, l4 = l >> 4;

  f32x4 acc[4][4];
#pragma unroll
  for (int i = 0; i < 4; ++i)
#pragma unroll
    for (int j = 0; j < 4; ++j) acc[i][j] = (f32x4){0.f, 0.f, 0.f, 0.f};

  for (int kt = 0; kt < 6; ++kt) {
    int k0 = kt * 64;
#pragma unroll
    for (int i = 0; i < 4; ++i) {
      int chunk = tid + 256 * i;
      int row = chunk >> 3;
      int c8 = (chunk & 7) * 8;
      bf16x8 v = *(const bf16x8*)&att[(size_t)(m0 + row) * Cn + k0 + c8];
      *(bf16x8*)&As[row * 64 + swz(row, c8)] = v;
    }
#pragma unroll
    for (int i = 0; i < 4; ++i) {
      int chunk = tid + 256 * i;
      int row = chunk >> 3;
      int c8 = (chunk & 7) * 8;
      bf16x8 t = load_cvt8(Wp + (size_t)(n0 + row) * Cn + k0 + c8);
      *(bf16x8*)&Bs[row * 64 + swz(row, c8)] = t;
    }
    __syncthreads();
#pragma unroll
    for (int kk = 0; kk < 2; ++kk) {
      bf16x8 a[4], bb[4];
#pragma unroll
      for (int rt = 0; rt < 4; ++rt) {
        int row = wr * 64 + rt * 16 + l16;
        a[rt] = *(const bf16x8*)&As[row * 64 + swz(row, kk * 32 + l4 * 8)];
      }
#pragma unroll
      for (int ct = 0; ct < 4; ++ct) {
        int row = wc * 64 + ct * 16 + l16;
        bb[ct] = *(const bf16x8*)&Bs[row * 64 + swz(row, kk * 32 + l4 * 8)];
      }
#pragma unroll
      for (int rt = 0; rt < 4; ++rt)
#pragma unroll
        for (int ct = 0; ct < 4; ++ct)
          acc[rt][ct] = __builtin_amdgcn_mfma_f32_16x16x32_bf16(a[rt], bb[ct],
                                                                acc[rt][ct], 0, 0, 0);
    }
    __syncthreads();
  }

#pragma unroll
  for (int ct = 0; ct < 4; ++ct) {
    int n = n0 + wc * 64 + ct * 16 + l16;
    float bias = bp[n];
#pragma unroll
    for (int rt = 0; rt < 4; ++rt)
#pragma unroll
      for (int rr = 0; rr < 4; ++rr) {
        int m = m0 + wr * 64 + rt * 16 + l4 * 4 + rr;
        out[(size_t)m * Cn + n] = acc[rt][ct][rr] + bias;
      }
  }
}

extern "C" void kernel_launch(void* const* d_in, const int* in_sizes, int n_in,
                              void* d_out, int out_size, void* d_ws, size_t ws_size,
                              hipStream_t stream) {
  const float* x  = (const float*)d_in[0];
  const float* Wk = (const float*)d_in[1];
  const float* Wq = (const float*)d_in[2];
  const float* Wv = (const float*)d_in[3];
  const float* Wp = (const float*)d_in[4];
  const float* bp = (const float*)d_in[5];
  float* out = (float*)d_out;

  const size_t E2 = (size_t)Bn * Tn * Cn * 2;  // 50331648 bytes per bf16 buffer
  __bf16* att = (__bf16*)d_ws;

  if (ws_size >= 4 * E2) {
    __bf16* qb = (__bf16*)((char*)d_ws + E2);
    __bf16* kb = (__bf16*)((char*)d_ws + 2 * E2);
    __bf16* vt = (__bf16*)((char*)d_ws + 3 * E2);
    qkv_gemm<<<4608, 256, 0, stream>>>(x, Wq, Wk, Wv, qb, kb, vt);
    attn2<<<3072, 256, 0, stream>>>(qb, kb, vt, att);
  } else {
    attn_fused<<<Bn * Hn, 256, 0, stream>>>(x, Wk, Wq, Wv, att);
  }
  proj_kernel<<<512 * 3, 256, 0, stream>>>(att, Wp, bp, out);
}

// Round 3
// 326.215 us; speedup vs baseline: 1.4921x; 1.0378x over previous
//
#include <hip/hip_runtime.h>
#include <hip/hip_bf16.h>

#define Bn 256
#define Tn 256
#define Cn 384
#define Hn 6
#define HSn 64

typedef __attribute__((ext_vector_type(8))) __bf16 bf16x8;
typedef __attribute__((ext_vector_type(4))) float f32x4;

// XOR swizzle in ELEMENT units for bf16 tiles with 64-elem (128B) rows.
__device__ __forceinline__ int swz(int row, int col) {
  return col ^ ((row & 7) << 3);
}

__device__ __forceinline__ bf16x8 load_cvt8(const float* src) {
  f32x4 f0 = *(const f32x4*)(src);
  f32x4 f1 = *(const f32x4*)(src + 4);
  bf16x8 t;
  t[0] = (__bf16)f0[0]; t[1] = (__bf16)f0[1];
  t[2] = (__bf16)f0[2]; t[3] = (__bf16)f0[3];
  t[4] = (__bf16)f1[0]; t[5] = (__bf16)f1[1];
  t[6] = (__bf16)f1[2]; t[7] = (__bf16)f1[3];
  return t;
}

// Async global->LDS, 16B per lane. LDS dest = wave-uniform base + lane*16;
// callers keep dest linear in tid and bake swizzles into the SOURCE image.
typedef const __attribute__((address_space(1))) unsigned int* gp_t;
typedef __attribute__((address_space(3))) unsigned int* lp_t;
__device__ __forceinline__ void gload16(const void* g, void* l) {
  __builtin_amdgcn_global_load_lds((gp_t)g, (lp_t)l, 16, 0, 0);
}

// ---------------------------------------------------------------------------
// K0: convert x (f32) to bf16 LDS-image tiles: [bm 512][kt 6][128 r][64 c]
// element (r,c) at tile*8192 + r*64 + swz(r, c&~7) + (c&7).
// ---------------------------------------------------------------------------
__global__ __launch_bounds__(256, 4)
void cvt_x(const float* __restrict__ x, __bf16* __restrict__ xb) {
  int tt = blockIdx.x;            // tile id, 3072 total
  int bm = tt / 6, kt = tt % 6;
  int tid = threadIdx.x;
#pragma unroll
  for (int i = 0; i < 4; ++i) {
    int chunk = tid + 256 * i;    // 0..1023
    int row = chunk >> 3;
    int c8 = (chunk & 7) * 8;
    bf16x8 v = load_cvt8(x + (size_t)(bm * 128 + row) * Cn + kt * 64 + c8);
    *(bf16x8*)&xb[(size_t)tt * 8192 + row * 64 + swz(row, c8)] = v;
  }
}

// ---------------------------------------------------------------------------
// K1: QKV GEMM, M=65536, N=1152, K=384. 128x128 tiles, 256 thr.
// A: async gload_lds from pre-tiled xb (double-buffered).
// B: full 128x384 W panel staged once (reg path, f32->bf16, Q pre-scaled).
// Outputs Q/K in [b][h][jt 4][64 t][64 d] swizzled tiles; V as [..][64 d][64 t].
// ---------------------------------------------------------------------------
__global__ __launch_bounds__(256, 2)
void qkv_gemm(const __bf16* __restrict__ xb, const float* __restrict__ Wq,
              const float* __restrict__ Wk, const float* __restrict__ Wv,
              __bf16* __restrict__ qt_, __bf16* __restrict__ kt_,
              __bf16* __restrict__ vt_) {
  __shared__ __bf16 Bs[6 * 8192];   // 48 KB: full B panel, 6 k-tiles
  __shared__ __bf16 As[2][8192];    // 32 KB: A dbuf

  int p = blockIdx.x;
  int wgid = (p & 7) * 576 + (p >> 3);   // 4608 blocks, bijective
  int bm = wgid / 9, bn = wgid % 9;
  const float* W = (bn < 3) ? Wq : (bn < 6) ? Wk : Wv;
  float scale = (bn < 3) ? 0.125f : 1.0f;
  int wrow0 = (bn % 3) * 128;

  int tid = threadIdx.x;
  int l = tid & 63, wid = tid >> 6;
  int wr = wid >> 1, wc = wid & 1;
  int l16 = l & 15, l4 = l >> 4;

  // ---- stage full B panel (once) -----------------------------------------
#pragma unroll
  for (int i = 0; i < 24; ++i) {
    int q = tid + 256 * i;          // 0..6143 chunks
    int kt = q >> 10;
    int rem = q & 1023;
    int row = rem >> 3;
    int c8 = (rem & 7) * 8;
    f32x4 f0 = *(const f32x4*)(W + (size_t)(wrow0 + row) * Cn + kt * 64 + c8);
    f32x4 f1 = *(const f32x4*)(W + (size_t)(wrow0 + row) * Cn + kt * 64 + c8 + 4);
    bf16x8 t;
    t[0] = (__bf16)(f0[0] * scale); t[1] = (__bf16)(f0[1] * scale);
    t[2] = (__bf16)(f0[2] * scale); t[3] = (__bf16)(f0[3] * scale);
    t[4] = (__bf16)(f1[0] * scale); t[5] = (__bf16)(f1[1] * scale);
    t[6] = (__bf16)(f1[2] * scale); t[7] = (__bf16)(f1[3] * scale);
    *(bf16x8*)&Bs[kt * 8192 + row * 64 + swz(row, c8)] = t;
  }

  // ---- stage A tile 0 (async) ---------------------------------------------
  const char* Asrc = (const char*)(xb + (size_t)bm * 6 * 8192);
#pragma unroll
  for (int i = 0; i < 4; ++i)
    gload16(Asrc + i * 4096 + tid * 16, (char*)&As[0][0] + i * 4096 + tid * 16);
  __syncthreads();

  f32x4 acc[4][4];
#pragma unroll
  for (int i = 0; i < 4; ++i)
#pragma unroll
    for (int j = 0; j < 4; ++j) acc[i][j] = (f32x4){0.f, 0.f, 0.f, 0.f};

  int cur = 0;
  for (int kt = 0; kt < 6; ++kt) {
    if (kt < 5) {
#pragma unroll
      for (int i = 0; i < 4; ++i)
        gload16(Asrc + (size_t)(kt + 1) * 16384 + i * 4096 + tid * 16,
                (char*)&As[cur ^ 1][0] + i * 4096 + tid * 16);
    }
#pragma unroll
    for (int kk = 0; kk < 2; ++kk) {
      bf16x8 a[4], bb[4];
#pragma unroll
      for (int rt = 0; rt < 4; ++rt) {
        int row = wr * 64 + rt * 16 + l16;
        a[rt] = *(const bf16x8*)&As[cur][row * 64 + swz(row, kk * 32 + l4 * 8)];
      }
#pragma unroll
      for (int ct = 0; ct < 4; ++ct) {
        int row = wc * 64 + ct * 16 + l16;
        bb[ct] = *(const bf16x8*)&Bs[kt * 8192 + row * 64 +
                                     swz(row, kk * 32 + l4 * 8)];
      }
#pragma unroll
      for (int rt = 0; rt < 4; ++rt)
#pragma unroll
        for (int ct = 0; ct < 4; ++ct)
          acc[rt][ct] = __builtin_amdgcn_mfma_f32_16x16x32_bf16(a[rt], bb[ct],
                                                                acc[rt][ct], 0, 0, 0);
    }
    __syncthreads();
    cur ^= 1;
  }

  int b = bm >> 1;
  int t0 = (bm & 1) * 128;

  if (bn < 6) {
    // Q/K: scatter 2B stores into swizzled [64t][64d] tiles.
    __bf16* ob = (bn < 3) ? qt_ : kt_;
    int nbase = (bn % 3) * 128;
#pragma unroll
    for (int ct = 0; ct < 4; ++ct) {
      int n = nbase + wc * 64 + ct * 16 + l16;
      int h = n >> 6, d = n & 63;
      __bf16* base = ob + ((size_t)(b * Hn + h) * 4) * 4096;
#pragma unroll
      for (int rt = 0; rt < 4; ++rt)
#pragma unroll
        for (int rr = 0; rr < 4; ++rr) {
          int t = t0 + wr * 64 + rt * 16 + l4 * 4 + rr;
          base[(size_t)(t >> 6) * 4096 + (t & 63) * 64 +
               (((d & ~7) ^ ((t & 7) << 3)) | (d & 7))] = (__bf16)acc[rt][ct][rr];
        }
    }
  } else {
    // V: transpose 128m x 128n tile through LDS (reuse As), store
    // [b][h][jt][64 d][64 t] swizzled tiles with 16B stores.
    __bf16* Tr = &As[0][0];
#pragma unroll
    for (int ct = 0; ct < 4; ++ct)
#pragma unroll
      for (int rt = 0; rt < 4; ++rt)
#pragma unroll
        for (int rr = 0; rr < 4; ++rr) {
          int nl = wc * 64 + ct * 16 + l16;
          int ml = wr * 64 + rt * 16 + l4 * 4 + rr;
          Tr[nl * 128 + (ml ^ ((nl & 7) << 3))] = (__bf16)acc[rt][ct][rr];
        }
    __syncthreads();
    int nl = tid >> 1;
    int mh = (tid & 1) * 64;
    int vcol = (bn - 6) * 128 + nl;
    int h = vcol >> 6, d = vcol & 63;
    int jt = (t0 + mh) >> 6;
    __bf16* dst = vt_ + ((size_t)(b * Hn + h) * 4 + jt) * 4096;
#pragma unroll
    for (int c8 = 0; c8 < 8; ++c8) {
      bf16x8 v = *(const bf16x8*)&Tr[nl * 128 + ((mh + c8 * 8) ^ ((nl & 7) << 3))];
      *(bf16x8*)&dst[d * 64 + swz(d, c8 * 8)] = v;
    }
  }
}

// ---------------------------------------------------------------------------
// K2: flash attention from tiled Q/K/V. Block = (b, h, qt); 4 waves x 32 rows.
// All global reads via gload_lds from pre-swizzled tiles; K/V double-buffered.
// ---------------------------------------------------------------------------
__global__ __launch_bounds__(256, 2)
void attn3(const __bf16* __restrict__ qt_, const __bf16* __restrict__ kt_,
           const __bf16* __restrict__ vt_, __bf16* __restrict__ att) {
  __shared__ __bf16 Qs[2 * 4096];     // 16 KB, 2 q-tiles
  __shared__ __bf16 Kb[2][4096];      // 16 KB dbuf
  __shared__ __bf16 Vb[2][4096];      // 16 KB dbuf
  __shared__ __bf16 Pq[4][32 * 64];   // 16 KB

  int p = blockIdx.x;
  int wgid = (p & 7) * 384 + (p >> 3);
  int b = wgid / 12;
  int r = wgid % 12;
  int h = r >> 1, qt = r & 1;

  int tid = threadIdx.x, w = tid >> 6, l = tid & 63;
  int l16 = l & 15, l4 = l >> 4;

  size_t bh4 = ((size_t)b * Hn + h) * 4;
  const char* qsrc = (const char*)(qt_ + (bh4 + qt * 2) * 4096);
  const char* ksrc = (const char*)(kt_ + bh4 * 4096);
  const char* vsrc = (const char*)(vt_ + bh4 * 4096);

  int ntb = (qt + 1) * 2;                    // block tile count (2 or 4)
  int ntw = qt * 2 + 1 + (w >> 1);           // this wave's tile count
  int q0 = qt * 128 + w * 32;

  // stage Q (2 tiles) + K/V tile 0
#pragma unroll
  for (int i = 0; i < 4; ++i)
    gload16(qsrc + i * 4096 + tid * 16, (char*)Qs + i * 4096 + tid * 16);
#pragma unroll
  for (int i = 0; i < 2; ++i) {
    gload16(ksrc + i * 4096 + tid * 16, (char*)&Kb[0][0] + i * 4096 + tid * 16);
    gload16(vsrc + i * 4096 + tid * 16, (char*)&Vb[0][0] + i * 4096 + tid * 16);
  }
  __syncthreads();

  bf16x8 qa[2][2];
#pragma unroll
  for (int rt = 0; rt < 2; ++rt)
#pragma unroll
    for (int kk = 0; kk < 2; ++kk) {
      int row = (w & 1) * 32 + rt * 16 + l16;
      qa[rt][kk] = *(const bf16x8*)&Qs[(w >> 1) * 4096 + row * 64 +
                                       swz(row, kk * 32 + l4 * 8)];
    }

  const float LOG2E = 1.44269504088896f;
  f32x4 o[2][4];
  f32x4 m_[2], lsum[2];
#pragma unroll
  for (int i = 0; i < 2; ++i) {
#pragma unroll
    for (int j = 0; j < 4; ++j) o[i][j] = (f32x4){0.f, 0.f, 0.f, 0.f};
    m_[i] = (f32x4){-1e30f, -1e30f, -1e30f, -1e30f};
    lsum[i] = (f32x4){0.f, 0.f, 0.f, 0.f};
  }

  int cur = 0;
  for (int jt = 0; jt < ntb; ++jt) {
    if (jt + 1 < ntb) {
#pragma unroll
      for (int i = 0; i < 2; ++i) {
        gload16(ksrc + (size_t)(jt + 1) * 8192 + i * 4096 + tid * 16,
                (char*)&Kb[cur ^ 1][0] + i * 4096 + tid * 16);
        gload16(vsrc + (size_t)(jt + 1) * 8192 + i * 4096 + tid * 16,
                (char*)&Vb[cur ^ 1][0] + i * 4096 + tid * 16);
      }
    }

    if (jt < ntw) {
      f32x4 s[2][4];
#pragma unroll
      for (int i = 0; i < 2; ++i)
#pragma unroll
        for (int j = 0; j < 4; ++j) s[i][j] = (f32x4){0.f, 0.f, 0.f, 0.f};

#pragma unroll
      for (int kk = 0; kk < 2; ++kk)
#pragma unroll
        for (int ct = 0; ct < 4; ++ct) {
          int row = ct * 16 + l16;
          bf16x8 kf = *(const bf16x8*)&Kb[cur][row * 64 +
                                             swz(row, kk * 32 + l4 * 8)];
#pragma unroll
          for (int rt = 0; rt < 2; ++rt)
            s[rt][ct] = __builtin_amdgcn_mfma_f32_16x16x32_bf16(qa[rt][kk], kf,
                                                                s[rt][ct], 0, 0, 0);
        }

      if (jt == ntw - 1) {
#pragma unroll
        for (int rt = 0; rt < 2; ++rt)
#pragma unroll
          for (int ct = 0; ct < 4; ++ct)
#pragma unroll
            for (int rr = 0; rr < 4; ++rr) {
              int ql = q0 + rt * 16 + l4 * 4 + rr;
              int kl = jt * 64 + ct * 16 + l16;
              if (kl > ql) s[rt][ct][rr] = -1e30f;
            }
      }

#pragma unroll
      for (int rt = 0; rt < 2; ++rt) {
        float mt[4], corr[4], rsum[4];
#pragma unroll
        for (int rr = 0; rr < 4; ++rr)
          mt[rr] = fmaxf(fmaxf(s[rt][0][rr], s[rt][1][rr]),
                         fmaxf(s[rt][2][rr], s[rt][3][rr]));
#pragma unroll
        for (int off = 1; off < 16; off <<= 1)
#pragma unroll
          for (int rr = 0; rr < 4; ++rr)
            mt[rr] = fmaxf(mt[rr], __shfl_xor(mt[rr], off, 64));
#pragma unroll
        for (int rr = 0; rr < 4; ++rr) {
          float mnew = fmaxf(m_[rt][rr], mt[rr]);
          corr[rr] = exp2f((m_[rt][rr] - mnew) * LOG2E);
          m_[rt][rr] = mnew;
        }
#pragma unroll
        for (int ct = 0; ct < 4; ++ct)
#pragma unroll
          for (int rr = 0; rr < 4; ++rr)
            s[rt][ct][rr] = exp2f((s[rt][ct][rr] - m_[rt][rr]) * LOG2E);
#pragma unroll
        for (int rr = 0; rr < 4; ++rr)
          rsum[rr] = (s[rt][0][rr] + s[rt][1][rr]) + (s[rt][2][rr] + s[rt][3][rr]);
#pragma unroll
        for (int off = 1; off < 16; off <<= 1)
#pragma unroll
          for (int rr = 0; rr < 4; ++rr) rsum[rr] += __shfl_xor(rsum[rr], off, 64);
#pragma unroll
        for (int rr = 0; rr < 4; ++rr)
          lsum[rt][rr] = lsum[rt][rr] * corr[rr] + rsum[rr];
#pragma unroll
        for (int cd = 0; cd < 4; ++cd)
#pragma unroll
          for (int rr = 0; rr < 4; ++rr) o[rt][cd][rr] *= corr[rr];
#pragma unroll
        for (int ct = 0; ct < 4; ++ct)
#pragma unroll
          for (int rr = 0; rr < 4; ++rr) {
            int lr = rt * 16 + l4 * 4 + rr;
            Pq[w][lr * 64 + swz(lr, ct * 16 + l16)] = (__bf16)s[rt][ct][rr];
          }
      }

#pragma unroll
      for (int kk = 0; kk < 2; ++kk) {
        bf16x8 pa[2];
#pragma unroll
        for (int rt = 0; rt < 2; ++rt) {
          int row = rt * 16 + l16;
          pa[rt] = *(const bf16x8*)&Pq[w][row * 64 + swz(row, kk * 32 + l4 * 8)];
        }
#pragma unroll
        for (int cd = 0; cd < 4; ++cd) {
          int row = cd * 16 + l16;
          bf16x8 vf = *(const bf16x8*)&Vb[cur][row * 64 +
                                             swz(row, kk * 32 + l4 * 8)];
#pragma unroll
          for (int rt = 0; rt < 2; ++rt)
            o[rt][cd] = __builtin_amdgcn_mfma_f32_16x16x32_bf16(pa[rt], vf,
                                                                o[rt][cd], 0, 0, 0);
        }
      }
    }
    __syncthreads();
    cur ^= 1;
  }

#pragma unroll
  for (int rt = 0; rt < 2; ++rt)
#pragma unroll
    for (int cd = 0; cd < 4; ++cd)
#pragma unroll
      for (int rr = 0; rr < 4; ++rr) {
        int t = q0 + rt * 16 + l4 * 4 + rr;
        float val = o[rt][cd][rr] / lsum[rt][rr];
        att[((size_t)b * Tn + t) * Cn + h * HSn + cd * 16 + l16] = (__bf16)val;
      }
}

// ---------------------------------------------------------------------------
// K3: out = att @ Wp^T + bp   (M=65536, N=384, K=384), f32 output.
// ---------------------------------------------------------------------------
__global__ __launch_bounds__(256, 2)
void proj_kernel(const __bf16* __restrict__ att, const float* __restrict__ Wp,
                 const float* __restrict__ bp, float* __restrict__ out) {
  __shared__ __bf16 As[128 * 64];
  __shared__ __bf16 Bs[128 * 64];

  int bn = blockIdx.x / 512;
  int bm = blockIdx.x - bn * 512;
  int m0 = bm * 128, n0 = bn * 128;

  int tid = threadIdx.x;
  int l = tid & 63;
  int wid = tid >> 6;
  int wr = wid >> 1, wc = wid & 1;
  int l16 = l & 15, l4 = l >> 4;

  f32x4 acc[4][4];
#pragma unroll
  for (int i = 0; i < 4; ++i)
#pragma unroll
    for (int j = 0; j < 4; ++j) acc[i][j] = (f32x4){0.f, 0.f, 0.f, 0.f};

  for (int kt = 0; kt < 6; ++kt) {
    int k0 = kt * 64;
#pragma unroll
    for (int i = 0; i < 4; ++i) {
      int chunk = tid + 256 * i;
      int row = chunk >> 3;
      int c8 = (chunk & 7) * 8;
      bf16x8 v = *(const bf16x8*)&att[(size_t)(m0 + row) * Cn + k0 + c8];
      *(bf16x8*)&As[row * 64 + swz(row, c8)] = v;
    }
#pragma unroll
    for (int i = 0; i < 4; ++i) {
      int chunk = tid + 256 * i;
      int row = chunk >> 3;
      int c8 = (chunk & 7) * 8;
      bf16x8 t = load_cvt8(Wp + (size_t)(n0 + row) * Cn + k0 + c8);
      *(bf16x8*)&Bs[row * 64 + swz(row, c8)] = t;
    }
    __syncthreads();
#pragma unroll
    for (int kk = 0; kk < 2; ++kk) {
      bf16x8 a[4], bb[4];
#pragma unroll
      for (int rt = 0; rt < 4; ++rt) {
        int row = wr * 64 + rt * 16 + l16;
        a[rt] = *(const bf16x8*)&As[row * 64 + swz(row, kk * 32 + l4 * 8)];
      }
#pragma unroll
      for (int ct = 0; ct < 4; ++ct) {
        int row = wc * 64 + ct * 16 + l16;
        bb[ct] = *(const bf16x8*)&Bs[row * 64 + swz(row, kk * 32 + l4 * 8)];
      }
#pragma unroll
      for (int rt = 0; rt < 4; ++rt)
#pragma unroll
        for (int ct = 0; ct < 4; ++ct)
          acc[rt][ct] = __builtin_amdgcn_mfma_f32_16x16x32_bf16(a[rt], bb[ct],
                                                                acc[rt][ct], 0, 0, 0);
    }
    __syncthreads();
  }

#pragma unroll
  for (int ct = 0; ct < 4; ++ct) {
    int n = n0 + wc * 64 + ct * 16 + l16;
    float bias = bp[n];
#pragma unroll
    for (int rt = 0; rt < 4; ++rt)
#pragma unroll
      for (int rr = 0; rr < 4; ++rr) {
        int m = m0 + wr * 64 + rt * 16 + l4 * 4 + rr;
        out[(size_t)m * Cn + n] = acc[rt][ct][rr] + bias;
      }
  }
}

// ---------------------------------------------------------------------------
// Fallback (ws too small): fused QKV + attention per (b,h). Known-good.
// ---------------------------------------------------------------------------
__global__ __launch_bounds__(256, 1)
void attn_fused(const float* __restrict__ x, const float* __restrict__ Wk,
                const float* __restrict__ Wq, const float* __restrict__ Wv,
                __bf16* __restrict__ att) {
  __shared__ __bf16 Ks[Tn * HSn];
  __shared__ __bf16 Vt[HSn * Tn];
  __shared__ __bf16 Pq[4][64 * 64];

  int p = blockIdx.x;
  int r = p & 7;
  int q2 = p >> 3;
  int slot = q2 / Hn;
  int h = q2 - slot * Hn;
  int b = r + 8 * slot;

  int tid = threadIdx.x;
  int w = tid >> 6;
  int l = tid & 63;
  int l16 = l & 15;
  int l4 = l >> 4;

  const float* xb = x + (size_t)b * Tn * Cn;
  int qr = w * 64;

  f32x4 aq[4][4], ak[4][4], av[4][4];
#pragma unroll
  for (int i = 0; i < 4; ++i)
#pragma unroll
    for (int j = 0; j < 4; ++j) {
      aq[i][j] = (f32x4){0.f, 0.f, 0.f, 0.f};
      ak[i][j] = (f32x4){0.f, 0.f, 0.f, 0.f};
      av[i][j] = (f32x4){0.f, 0.f, 0.f, 0.f};
    }

  for (int ct6 = 0; ct6 < 6; ++ct6) {
    int c0 = ct6 * 64;
    bf16x8 a[4][2];
#pragma unroll
    for (int rt = 0; rt < 4; ++rt)
#pragma unroll
      for (int kk = 0; kk < 2; ++kk)
        a[rt][kk] =
            load_cvt8(xb + (size_t)(qr + rt * 16 + l16) * Cn + c0 + kk * 32 + l4 * 8);

    auto doMat = [&](const float* W, f32x4 (&acc)[4][4]) {
#pragma unroll
      for (int ct = 0; ct < 4; ++ct)
#pragma unroll
        for (int kk = 0; kk < 2; ++kk) {
          bf16x8 bb = load_cvt8(W + (size_t)(h * 64 + ct * 16 + l16) * Cn + c0 +
                                kk * 32 + l4 * 8);
#pragma unroll
          for (int rt = 0; rt < 4; ++rt)
            acc[rt][ct] = __builtin_amdgcn_mfma_f32_16x16x32_bf16(
                a[rt][kk], bb, acc[rt][ct], 0, 0, 0);
        }
    };
    doMat(Wq, aq);
    doMat(Wk, ak);
    doMat(Wv, av);
  }

#pragma unroll
  for (int rt = 0; rt < 4; ++rt)
#pragma unroll
    for (int ct = 0; ct < 4; ++ct)
#pragma unroll
      for (int rr = 0; rr < 4; ++rr) {
        int trow = qr + rt * 16 + l4 * 4 + rr;
        int col = ct * 16 + l16;
        Ks[trow * HSn + swz(trow, col)] = (__bf16)ak[rt][ct][rr];
        Vt[col * Tn + swz(col, trow)] = (__bf16)av[rt][ct][rr];
        int lrow = rt * 16 + l4 * 4 + rr;
        Pq[w][lrow * 64 + swz(lrow, col)] = (__bf16)(aq[rt][ct][rr] * 0.125f);
      }
  __syncthreads();

  bf16x8 qa[4][2];
#pragma unroll
  for (int rt = 0; rt < 4; ++rt)
#pragma unroll
    for (int kk = 0; kk < 2; ++kk) {
      int row = rt * 16 + l16;
      qa[rt][kk] = *(const bf16x8*)&Pq[w][row * 64 + swz(row, kk * 32 + l4 * 8)];
    }

  const float LOG2E = 1.44269504088896f;
  f32x4 o[4][4];
  f32x4 m_[4], lsum[4];
#pragma unroll
  for (int i = 0; i < 4; ++i) {
#pragma unroll
    for (int j = 0; j < 4; ++j) o[i][j] = (f32x4){0.f, 0.f, 0.f, 0.f};
    m_[i] = (f32x4){-1e30f, -1e30f, -1e30f, -1e30f};
    lsum[i] = (f32x4){0.f, 0.f, 0.f, 0.f};
  }

  for (int jt = 0; jt <= w; ++jt) {
    f32x4 s[4][4];
#pragma unroll
    for (int i = 0; i < 4; ++i)
#pragma unroll
      for (int j = 0; j < 4; ++j) s[i][j] = (f32x4){0.f, 0.f, 0.f, 0.f};

#pragma unroll
    for (int kk = 0; kk < 2; ++kk)
#pragma unroll
      for (int ct = 0; ct < 4; ++ct) {
        int key = jt * 64 + ct * 16 + l16;
        bf16x8 kf = *(const bf16x8*)&Ks[key * HSn + swz(key, kk * 32 + l4 * 8)];
#pragma unroll
        for (int rt = 0; rt < 4; ++rt)
          s[rt][ct] = __builtin_amdgcn_mfma_f32_16x16x32_bf16(qa[rt][kk], kf,
                                                              s[rt][ct], 0, 0, 0);
      }

    if (jt == w) {
#pragma unroll
      for (int rt = 0; rt < 4; ++rt)
#pragma unroll
        for (int ct = 0; ct < 4; ++ct)
#pragma unroll
          for (int rr = 0; rr < 4; ++rr) {
            int ql = rt * 16 + l4 * 4 + rr;
            int kl = ct * 16 + l16;
            if (kl > ql) s[rt][ct][rr] = -1e30f;
          }
    }

#pragma unroll
    for (int rt = 0; rt < 4; ++rt) {
      float mt[4], corr[4], rsum[4];
#pragma unroll
      for (int rr = 0; rr < 4; ++rr)
        mt[rr] = fmaxf(fmaxf(s[rt][0][rr], s[rt][1][rr]),
                       fmaxf(s[rt][2][rr], s[rt][3][rr]));
#pragma unroll
      for (int off = 1; off < 16; off <<= 1)
#pragma unroll
        for (int rr = 0; rr < 4; ++rr)
          mt[rr] = fmaxf(mt[rr], __shfl_xor(mt[rr], off, 64));
#pragma unroll
      for (int rr = 0; rr < 4; ++rr) {
        float mnew = fmaxf(m_[rt][rr], mt[rr]);
        corr[rr] = exp2f((m_[rt][rr] - mnew) * LOG2E);
        m_[rt][rr] = mnew;
      }
#pragma unroll
      for (int ct = 0; ct < 4; ++ct)
#pragma unroll
        for (int rr = 0; rr < 4; ++rr)
          s[rt][ct][rr] = exp2f((s[rt][ct][rr] - m_[rt][rr]) * LOG2E);
#pragma unroll
      for (int rr = 0; rr < 4; ++rr)
        rsum[rr] = (s[rt][0][rr] + s[rt][1][rr]) + (s[rt][2][rr] + s[rt][3][rr]);
#pragma unroll
      for (int off = 1; off < 16; off <<= 1)
#pragma unroll
        for (int rr = 0; rr < 4; ++rr) rsum[rr] += __shfl_xor(rsum[rr], off, 64);
#pragma unroll
      for (int rr = 0; rr < 4; ++rr)
        lsum[rt][rr] = lsum[rt][rr] * corr[rr] + rsum[rr];
#pragma unroll
      for (int cd = 0; cd < 4; ++cd)
#pragma unroll
        for (int rr = 0; rr < 4; ++rr) o[rt][cd][rr] *= corr[rr];

#pragma unroll
      for (int ct = 0; ct < 4; ++ct)
#pragma unroll
        for (int rr = 0; rr < 4; ++rr) {
          int lr = rt * 16 + l4 * 4 + rr;
          Pq[w][lr * 64 + swz(lr, ct * 16 + l16)] = (__bf16)s[rt][ct][rr];
        }
    }

#pragma unroll
    for (int kk = 0; kk < 2; ++kk) {
      bf16x8 pa[4];
#pragma unroll
      for (int rt = 0; rt < 4; ++rt) {
        int row = rt * 16 + l16;
        pa[rt] = *(const bf16x8*)&Pq[w][row * 64 + swz(row, kk * 32 + l4 * 8)];
      }
#pragma unroll
      for (int cd = 0; cd < 4; ++cd) {
        int drow = cd * 16 + l16;
        bf16x8 vb =
            *(const bf16x8*)&Vt[drow * Tn + swz(drow, jt * 64 + kk * 32 + l4 * 8)];
#pragma unroll
        for (int rt = 0; rt < 4; ++rt)
          o[rt][cd] = __builtin_amdgcn_mfma_f32_16x16x32_bf16(pa[rt], vb,
                                                              o[rt][cd], 0, 0, 0);
      }
    }
  }

  __bf16* ab = att + (size_t)b * Tn * Cn + h * HSn;
#pragma unroll
  for (int rt = 0; rt < 4; ++rt)
#pragma unroll
    for (int cd = 0; cd < 4; ++cd)
#pragma unroll
      for (int rr = 0; rr < 4; ++rr) {
        int trow = qr + rt * 16 + l4 * 4 + rr;
        float val = o[rt][cd][rr] / lsum[rt][rr];
        ab[(size_t)trow * Cn + cd * 16 + l16] = (__bf16)val;
      }
}

extern "C" void kernel_launch(void* const* d_in, const int* in_sizes, int n_in,
                              void* d_out, int out_size, void* d_ws, size_t ws_size,
                              hipStream_t stream) {
  const float* x  = (const float*)d_in[0];
  const float* Wk = (const float*)d_in[1];
  const float* Wq = (const float*)d_in[2];
  const float* Wv = (const float*)d_in[3];
  const float* Wp = (const float*)d_in[4];
  const float* bp = (const float*)d_in[5];
  float* out = (float*)d_out;

  const size_t E2 = (size_t)Bn * Tn * Cn * 2;  // 50331648 bytes
  __bf16* att = (__bf16*)d_ws;                 // region 0: xb then att

  if (ws_size >= 4 * E2) {
    __bf16* xb = (__bf16*)d_ws;                        // region 0 (pre-attn)
    __bf16* qt_ = (__bf16*)((char*)d_ws + E2);
    __bf16* kt_ = (__bf16*)((char*)d_ws + 2 * E2);
    __bf16* vt_ = (__bf16*)((char*)d_ws + 3 * E2);
    cvt_x<<<3072, 256, 0, stream>>>(x, xb);
    qkv_gemm<<<4608, 256, 0, stream>>>(xb, Wq, Wk, Wv, qt_, kt_, vt_);
    attn3<<<3072, 256, 0, stream>>>(qt_, kt_, vt_, att);
  } else {
    attn_fused<<<Bn * Hn, 256, 0, stream>>>(x, Wk, Wq, Wv, att);
  }
  proj_kernel<<<512 * 3, 256, 0, stream>>>(att, Wp, bp, out);
}

// Round 4
// 317.618 us; speedup vs baseline: 1.5325x; 1.0271x over previous
//
#include <hip/hip_runtime.h>
#include <hip/hip_bf16.h>

#define Bn 256
#define Tn 256
#define Cn 384
#define Hn 6
#define HSn 64

typedef __attribute__((ext_vector_type(8))) __bf16 bf16x8;
typedef __attribute__((ext_vector_type(4))) float f32x4;

// XOR swizzle in ELEMENT units for bf16 tiles with 64-elem (128B) rows.
__device__ __forceinline__ int swz(int row, int col) {
  return col ^ ((row & 7) << 3);
}

__device__ __forceinline__ bf16x8 load_cvt8(const float* src) {
  f32x4 f0 = *(const f32x4*)(src);
  f32x4 f1 = *(const f32x4*)(src + 4);
  bf16x8 t;
  t[0] = (__bf16)f0[0]; t[1] = (__bf16)f0[1];
  t[2] = (__bf16)f0[2]; t[3] = (__bf16)f0[3];
  t[4] = (__bf16)f1[0]; t[5] = (__bf16)f1[1];
  t[6] = (__bf16)f1[2]; t[7] = (__bf16)f1[3];
  return t;
}

// Async global->LDS, 16B per lane; LDS dest linear in tid, swizzle baked
// into the SOURCE image (rule #21: both-sides-or-neither).
typedef const __attribute__((address_space(1))) unsigned int* gp_t;
typedef __attribute__((address_space(3))) unsigned int* lp_t;
__device__ __forceinline__ void gload16(const void* g, void* l) {
  __builtin_amdgcn_global_load_lds((gp_t)g, (lp_t)l, 16, 0, 0);
}

// ---------------------------------------------------------------------------
// K0: convert x (f32) to bf16 LDS-image tiles: [bm 512][kt 6][128 r][64 c],
// element (r,c) at tile*8192 + r*64 + swz(r, c&~7) + (c&7).
// ---------------------------------------------------------------------------
__global__ __launch_bounds__(256, 4)
void cvt_x(const float* __restrict__ x, __bf16* __restrict__ xb) {
  int tt = blockIdx.x;            // tile id, 3072 total
  int bm = tt / 6, kt = tt % 6;
  int tid = threadIdx.x;
#pragma unroll
  for (int i = 0; i < 4; ++i) {
    int chunk = tid + 256 * i;    // 0..1023
    int row = chunk >> 3;
    int c8 = (chunk & 7) * 8;
    bf16x8 v = load_cvt8(x + (size_t)(bm * 128 + row) * Cn + kt * 64 + c8);
    *(bf16x8*)&xb[(size_t)tt * 8192 + row * 64 + swz(row, c8)] = v;
  }
}

// ---------------------------------------------------------------------------
// K1: QKV GEMM, M=65536, N=1152, K=384. 128x128 tiles, 256 thr, 64 KB LDS
// (2 blocks/CU). A: async gload_lds dbuf from xb tiles. B: reg-path f32->bf16
// dbuf (Q pre-scaled 0.125). Epilogues relayout through LDS for 16B stores.
// Q/K out: [b][h][jt 4][64 t][64 d] swizzled tiles; V out: [..][64 d][64 t].
// ---------------------------------------------------------------------------
__global__ __launch_bounds__(256, 2)
void qkv_gemm(const __bf16* __restrict__ xb, const float* __restrict__ Wq,
              const float* __restrict__ Wk, const float* __restrict__ Wv,
              __bf16* __restrict__ qt_, __bf16* __restrict__ kt_,
              __bf16* __restrict__ vt_) {
  __shared__ __bf16 As[2][8192];    // 32 KB (also reused as 128x128 Tr)
  __shared__ __bf16 Bs[2][8192];    // 32 KB

  int p = blockIdx.x;
  int wgid = (p & 7) * 576 + (p >> 3);   // 4608 blocks, bijective
  int bm = wgid / 9, bn = wgid % 9;
  const float* W = (bn < 3) ? Wq : (bn < 6) ? Wk : Wv;
  float scale = (bn < 3) ? 0.125f : 1.0f;
  int wrow0 = (bn % 3) * 128;

  int tid = threadIdx.x;
  int l = tid & 63, wid = tid >> 6;
  int wr = wid >> 1, wc = wid & 1;
  int l16 = l & 15, l4 = l >> 4;

  const char* Asrc = (const char*)(xb + (size_t)bm * 6 * 8192);

  // prologue: A0 async + B0 reg path
#pragma unroll
  for (int i = 0; i < 4; ++i)
    gload16(Asrc + i * 4096 + tid * 16, (char*)&As[0][0] + i * 4096 + tid * 16);
#pragma unroll
  for (int i = 0; i < 4; ++i) {
    int c = tid + 256 * i;
    int row = c >> 3, c8 = (c & 7) * 8;
    f32x4 f0 = *(const f32x4*)(W + (size_t)(wrow0 + row) * Cn + c8);
    f32x4 f1 = *(const f32x4*)(W + (size_t)(wrow0 + row) * Cn + c8 + 4);
    bf16x8 t;
    t[0] = (__bf16)(f0[0] * scale); t[1] = (__bf16)(f0[1] * scale);
    t[2] = (__bf16)(f0[2] * scale); t[3] = (__bf16)(f0[3] * scale);
    t[4] = (__bf16)(f1[0] * scale); t[5] = (__bf16)(f1[1] * scale);
    t[6] = (__bf16)(f1[2] * scale); t[7] = (__bf16)(f1[3] * scale);
    *(bf16x8*)&Bs[0][row * 64 + swz(row, c8)] = t;
  }
  __syncthreads();

  f32x4 acc[4][4];
#pragma unroll
  for (int i = 0; i < 4; ++i)
#pragma unroll
    for (int j = 0; j < 4; ++j) acc[i][j] = (f32x4){0.f, 0.f, 0.f, 0.f};

  int cur = 0;
  for (int kt = 0; kt < 6; ++kt) {
    f32x4 b0[4], b1[4];
    if (kt < 5) {
#pragma unroll
      for (int i = 0; i < 4; ++i)
        gload16(Asrc + (size_t)(kt + 1) * 16384 + i * 4096 + tid * 16,
                (char*)&As[cur ^ 1][0] + i * 4096 + tid * 16);
#pragma unroll
      for (int i = 0; i < 4; ++i) {
        int c = tid + 256 * i;
        int row = c >> 3, c8 = (c & 7) * 8;
        const float* src = W + (size_t)(wrow0 + row) * Cn + (kt + 1) * 64 + c8;
        b0[i] = *(const f32x4*)src;
        b1[i] = *(const f32x4*)(src + 4);
      }
    }
#pragma unroll
    for (int kk = 0; kk < 2; ++kk) {
      bf16x8 a[4], bb[4];
#pragma unroll
      for (int rt = 0; rt < 4; ++rt) {
        int row = wr * 64 + rt * 16 + l16;
        a[rt] = *(const bf16x8*)&As[cur][row * 64 + swz(row, kk * 32 + l4 * 8)];
      }
#pragma unroll
      for (int ct = 0; ct < 4; ++ct) {
        int row = wc * 64 + ct * 16 + l16;
        bb[ct] = *(const bf16x8*)&Bs[cur][row * 64 + swz(row, kk * 32 + l4 * 8)];
      }
#pragma unroll
      for (int rt = 0; rt < 4; ++rt)
#pragma unroll
        for (int ct = 0; ct < 4; ++ct)
          acc[rt][ct] = __builtin_amdgcn_mfma_f32_16x16x32_bf16(a[rt], bb[ct],
                                                                acc[rt][ct], 0, 0, 0);
    }
    if (kt < 5) {
#pragma unroll
      for (int i = 0; i < 4; ++i) {
        int c = tid + 256 * i;
        int row = c >> 3, c8 = (c & 7) * 8;
        bf16x8 t;
        t[0] = (__bf16)(b0[i][0] * scale); t[1] = (__bf16)(b0[i][1] * scale);
        t[2] = (__bf16)(b0[i][2] * scale); t[3] = (__bf16)(b0[i][3] * scale);
        t[4] = (__bf16)(b1[i][0] * scale); t[5] = (__bf16)(b1[i][1] * scale);
        t[6] = (__bf16)(b1[i][2] * scale); t[7] = (__bf16)(b1[i][3] * scale);
        *(bf16x8*)&Bs[cur ^ 1][row * 64 + swz(row, c8)] = t;
      }
    }
    __syncthreads();
    cur ^= 1;
  }

  int b = bm >> 1;
  int t0 = (bm & 1) * 128;
  __bf16* Tr = &As[0][0];            // 128x128 = 32 KB relayout buffer

  if (bn < 6) {
    // Q/K: [t][n] into Tr (swizzled by t), then 16B stores to [t][d] tiles.
    __bf16* ob = (bn < 3) ? qt_ : kt_;
#pragma unroll
    for (int ct = 0; ct < 4; ++ct)
#pragma unroll
      for (int rt = 0; rt < 4; ++rt)
#pragma unroll
        for (int rr = 0; rr < 4; ++rr) {
          int tl = wr * 64 + rt * 16 + l4 * 4 + rr;
          int nl = wc * 64 + ct * 16 + l16;
          Tr[tl * 128 + (nl ^ ((tl & 7) << 3))] = (__bf16)acc[rt][ct][rr];
        }
    __syncthreads();
    int tl = tid >> 1;
    int nh = (tid & 1) * 64;
    int h = (bn % 3) * 2 + (tid & 1);
    int t = t0 + tl;
    __bf16* dst = ob + ((size_t)(b * Hn + h) * 4 + (t >> 6)) * 4096 + (t & 63) * 64;
#pragma unroll
    for (int c8 = 0; c8 < 8; ++c8) {
      bf16x8 v = *(const bf16x8*)&Tr[tl * 128 + ((nh + c8 * 8) ^ ((tl & 7) << 3))];
      *(bf16x8*)&dst[swz(t, c8 * 8)] = v;
    }
  } else {
    // V: transpose through Tr, store [b][h][jt][64 d][64 t] swizzled tiles.
#pragma unroll
    for (int ct = 0; ct < 4; ++ct)
#pragma unroll
      for (int rt = 0; rt < 4; ++rt)
#pragma unroll
        for (int rr = 0; rr < 4; ++rr) {
          int nl = wc * 64 + ct * 16 + l16;
          int ml = wr * 64 + rt * 16 + l4 * 4 + rr;
          Tr[nl * 128 + (ml ^ ((nl & 7) << 3))] = (__bf16)acc[rt][ct][rr];
        }
    __syncthreads();
    int nl = tid >> 1;
    int mh = (tid & 1) * 64;
    int vcol = (bn - 6) * 128 + nl;
    int h = vcol >> 6, d = vcol & 63;
    int jt = (t0 + mh) >> 6;
    __bf16* dst = vt_ + ((size_t)(b * Hn + h) * 4 + jt) * 4096;
#pragma unroll
    for (int c8 = 0; c8 < 8; ++c8) {
      bf16x8 v = *(const bf16x8*)&Tr[nl * 128 + ((mh + c8 * 8) ^ ((nl & 7) << 3))];
      *(bf16x8*)&dst[d * 64 + swz(d, c8 * 8)] = v;
    }
  }
}

// ---------------------------------------------------------------------------
// K2: flash attention, one block per (b,h), 4 waves. Wave w owns stripe pair
// {32w, 224-32w} (32 q-rows each) -> every wave computes exactly 5 causal
// stripe-tiles (perfect balance). K/V staged once, double-buffered, async.
// ---------------------------------------------------------------------------
__global__ __launch_bounds__(256, 2)
void attn4(const __bf16* __restrict__ qt_, const __bf16* __restrict__ kt_,
           const __bf16* __restrict__ vt_, __bf16* __restrict__ att) {
  __shared__ __bf16 Qs[4 * 4096];     // 32 KB, all 4 q-tiles
  __shared__ __bf16 Kb[2][4096];      // 16 KB dbuf
  __shared__ __bf16 Vb[2][4096];      // 16 KB dbuf
  __shared__ __bf16 Pq[4][32 * 64];   // 16 KB

  int p = blockIdx.x;
  int wgid = (p & 7) * 192 + (p >> 3);   // 1536 blocks, bijective
  int b = wgid / 6;
  int h = wgid % 6;

  int tid = threadIdx.x, w = tid >> 6, l = tid & 63;
  int l16 = l & 15, l4 = l >> 4;

  const __bf16* tb = qt_ + ((size_t)b * Hn + h) * 4 * 4096;
  const char* qsrc = (const char*)tb;
  const char* ksrc = (const char*)(kt_ + ((size_t)b * Hn + h) * 4 * 4096);
  const char* vsrc = (const char*)(vt_ + ((size_t)b * Hn + h) * 4 * 4096);
  (void)tb;

  // stage all Q (32 KB) + K/V tile 0
#pragma unroll
  for (int i = 0; i < 8; ++i)
    gload16(qsrc + i * 4096 + tid * 16, (char*)Qs + i * 4096 + tid * 16);
#pragma unroll
  for (int i = 0; i < 2; ++i) {
    gload16(ksrc + i * 4096 + tid * 16, (char*)&Kb[0][0] + i * 4096 + tid * 16);
    gload16(vsrc + i * 4096 + tid * 16, (char*)&Vb[0][0] + i * 4096 + tid * 16);
  }
  __syncthreads();

  int sA = w, sB = 7 - w;              // stripe ids (32 rows each)
  bf16x8 qa[2][2][2];                  // [stripe][rt][kk]
#pragma unroll
  for (int si = 0; si < 2; ++si) {
    int s = si ? sB : sA;
#pragma unroll
    for (int rt = 0; rt < 2; ++rt)
#pragma unroll
      for (int kk = 0; kk < 2; ++kk) {
        int row = s * 32 + rt * 16 + l16;       // global q row
        qa[si][rt][kk] = *(const bf16x8*)&Qs[(row >> 6) * 4096 + (row & 63) * 64 +
                                             swz(row & 63, kk * 32 + l4 * 8)];
      }
  }

  const float LOG2E = 1.44269504088896f;
  f32x4 o[2][2][4];                    // [stripe][rt][cd]
  f32x4 m_[2][2], lsum[2][2];
#pragma unroll
  for (int si = 0; si < 2; ++si)
#pragma unroll
    for (int rt = 0; rt < 2; ++rt) {
#pragma unroll
      for (int cd = 0; cd < 4; ++cd) o[si][rt][cd] = (f32x4){0.f, 0.f, 0.f, 0.f};
      m_[si][rt] = (f32x4){-1e30f, -1e30f, -1e30f, -1e30f};
      lsum[si][rt] = (f32x4){0.f, 0.f, 0.f, 0.f};
    }

  int cur = 0;
  for (int jt = 0; jt < 4; ++jt) {
    if (jt < 3) {
#pragma unroll
      for (int i = 0; i < 2; ++i) {
        gload16(ksrc + (size_t)(jt + 1) * 8192 + i * 4096 + tid * 16,
                (char*)&Kb[cur ^ 1][0] + i * 4096 + tid * 16);
        gload16(vsrc + (size_t)(jt + 1) * 8192 + i * 4096 + tid * 16,
                (char*)&Vb[cur ^ 1][0] + i * 4096 + tid * 16);
      }
    }

#pragma unroll
    for (int si = 0; si < 2; ++si) {
      int s = si ? sB : sA;
      if (jt > (s >> 1)) continue;     // causal: stripe s needs tiles 0..s/2

      f32x4 sv[2][4];
#pragma unroll
      for (int i = 0; i < 2; ++i)
#pragma unroll
        for (int j = 0; j < 4; ++j) sv[i][j] = (f32x4){0.f, 0.f, 0.f, 0.f};

#pragma unroll
      for (int kk = 0; kk < 2; ++kk)
#pragma unroll
        for (int ct = 0; ct < 4; ++ct) {
          int row = ct * 16 + l16;
          bf16x8 kf = *(const bf16x8*)&Kb[cur][row * 64 +
                                             swz(row, kk * 32 + l4 * 8)];
#pragma unroll
          for (int rt = 0; rt < 2; ++rt)
            sv[rt][ct] = __builtin_amdgcn_mfma_f32_16x16x32_bf16(
                qa[si][rt][kk], kf, sv[rt][ct], 0, 0, 0);
        }

      if (jt == (s >> 1)) {            // diagonal tile: causal mask
#pragma unroll
        for (int rt = 0; rt < 2; ++rt)
#pragma unroll
          for (int ct = 0; ct < 4; ++ct)
#pragma unroll
            for (int rr = 0; rr < 4; ++rr) {
              int ql = s * 32 + rt * 16 + l4 * 4 + rr;
              int kl = jt * 64 + ct * 16 + l16;
              if (kl > ql) sv[rt][ct][rr] = -1e30f;
            }
      }

#pragma unroll
      for (int rt = 0; rt < 2; ++rt) {
        float mt[4], corr[4], rsum[4];
#pragma unroll
        for (int rr = 0; rr < 4; ++rr)
          mt[rr] = fmaxf(fmaxf(sv[rt][0][rr], sv[rt][1][rr]),
                         fmaxf(sv[rt][2][rr], sv[rt][3][rr]));
#pragma unroll
        for (int off = 1; off < 16; off <<= 1)
#pragma unroll
          for (int rr = 0; rr < 4; ++rr)
            mt[rr] = fmaxf(mt[rr], __shfl_xor(mt[rr], off, 64));
#pragma unroll
        for (int rr = 0; rr < 4; ++rr) {
          float mnew = fmaxf(m_[si][rt][rr], mt[rr]);
          corr[rr] = exp2f((m_[si][rt][rr] - mnew) * LOG2E);
          m_[si][rt][rr] = mnew;
        }
#pragma unroll
        for (int ct = 0; ct < 4; ++ct)
#pragma unroll
          for (int rr = 0; rr < 4; ++rr)
            sv[rt][ct][rr] = exp2f((sv[rt][ct][rr] - m_[si][rt][rr]) * LOG2E);
#pragma unroll
        for (int rr = 0; rr < 4; ++rr)
          rsum[rr] = (sv[rt][0][rr] + sv[rt][1][rr]) + (sv[rt][2][rr] + sv[rt][3][rr]);
#pragma unroll
        for (int off = 1; off < 16; off <<= 1)
#pragma unroll
          for (int rr = 0; rr < 4; ++rr) rsum[rr] += __shfl_xor(rsum[rr], off, 64);
#pragma unroll
        for (int rr = 0; rr < 4; ++rr)
          lsum[si][rt][rr] = lsum[si][rt][rr] * corr[rr] + rsum[rr];
#pragma unroll
        for (int cd = 0; cd < 4; ++cd)
#pragma unroll
          for (int rr = 0; rr < 4; ++rr) o[si][rt][cd][rr] *= corr[rr];
#pragma unroll
        for (int ct = 0; ct < 4; ++ct)
#pragma unroll
          for (int rr = 0; rr < 4; ++rr) {
            int lr = rt * 16 + l4 * 4 + rr;
            Pq[w][lr * 64 + swz(lr, ct * 16 + l16)] = (__bf16)sv[rt][ct][rr];
          }
      }

#pragma unroll
      for (int kk = 0; kk < 2; ++kk) {
        bf16x8 pa[2];
#pragma unroll
        for (int rt = 0; rt < 2; ++rt) {
          int row = rt * 16 + l16;
          pa[rt] = *(const bf16x8*)&Pq[w][row * 64 + swz(row, kk * 32 + l4 * 8)];
        }
#pragma unroll
        for (int cd = 0; cd < 4; ++cd) {
          int row = cd * 16 + l16;
          bf16x8 vf = *(const bf16x8*)&Vb[cur][row * 64 +
                                             swz(row, kk * 32 + l4 * 8)];
#pragma unroll
          for (int rt = 0; rt < 2; ++rt)
            o[si][rt][cd] = __builtin_amdgcn_mfma_f32_16x16x32_bf16(
                pa[rt], vf, o[si][rt][cd], 0, 0, 0);
        }
      }
    }
    __syncthreads();
    cur ^= 1;
  }

#pragma unroll
  for (int si = 0; si < 2; ++si) {
    int s = si ? sB : sA;
#pragma unroll
    for (int rt = 0; rt < 2; ++rt)
#pragma unroll
      for (int cd = 0; cd < 4; ++cd)
#pragma unroll
        for (int rr = 0; rr < 4; ++rr) {
          int t = s * 32 + rt * 16 + l4 * 4 + rr;
          float val = o[si][rt][cd][rr] / lsum[si][rt][rr];
          att[((size_t)b * Tn + t) * Cn + h * HSn + cd * 16 + l16] = (__bf16)val;
        }
  }
}

// ---------------------------------------------------------------------------
// K3: out = att @ Wp^T + bp   (M=65536, N=384, K=384), f32 output.
// ---------------------------------------------------------------------------
__global__ __launch_bounds__(256, 2)
void proj_kernel(const __bf16* __restrict__ att, const float* __restrict__ Wp,
                 const float* __restrict__ bp, float* __restrict__ out) {
  __shared__ __bf16 As[128 * 64];
  __shared__ __bf16 Bs[128 * 64];

  int bn = blockIdx.x / 512;
  int bm = blockIdx.x - bn * 512;
  int m0 = bm * 128, n0 = bn * 128;

  int tid = threadIdx.x;
  int l = tid & 63;
  int wid = tid >> 6;
  int wr = wid >> 1, wc = wid & 1;
  int l16 = l & 15, l4 = l >> 4;

  f32x4 acc[4][4];
#pragma unroll
  for (int i = 0; i < 4; ++i)
#pragma unroll
    for (int j = 0; j < 4; ++j) acc[i][j] = (f32x4){0.f, 0.f, 0.f, 0.f};

  for (int kt = 0; kt < 6; ++kt) {
    int k0 = kt * 64;
#pragma unroll
    for (int i = 0; i < 4; ++i) {
      int chunk = tid + 256 * i;
      int row = chunk >> 3;
      int c8 = (chunk & 7) * 8;
      bf16x8 v = *(const bf16x8*)&att[(size_t)(m0 + row) * Cn + k0 + c8];
      *(bf16x8*)&As[row * 64 + swz(row, c8)] = v;
    }
#pragma unroll
    for (int i = 0; i < 4; ++i) {
      int chunk = tid + 256 * i;
      int row = chunk >> 3;
      int c8 = (chunk & 7) * 8;
      bf16x8 t = load_cvt8(Wp + (size_t)(n0 + row) * Cn + k0 + c8);
      *(bf16x8*)&Bs[row * 64 + swz(row, c8)] = t;
    }
    __syncthreads();
#pragma unroll
    for (int kk = 0; kk < 2; ++kk) {
      bf16x8 a[4], bb[4];
#pragma unroll
      for (int rt = 0; rt < 4; ++rt) {
        int row = wr * 64 + rt * 16 + l16;
        a[rt] = *(const bf16x8*)&As[row * 64 + swz(row, kk * 32 + l4 * 8)];
      }
#pragma unroll
      for (int ct = 0; ct < 4; ++ct) {
        int row = wc * 64 + ct * 16 + l16;
        bb[ct] = *(const bf16x8*)&Bs[row * 64 + swz(row, kk * 32 + l4 * 8)];
      }
#pragma unroll
      for (int rt = 0; rt < 4; ++rt)
#pragma unroll
        for (int ct = 0; ct < 4; ++ct)
          acc[rt][ct] = __builtin_amdgcn_mfma_f32_16x16x32_bf16(a[rt], bb[ct],
                                                                acc[rt][ct], 0, 0, 0);
    }
    __syncthreads();
  }

#pragma unroll
  for (int ct = 0; ct < 4; ++ct) {
    int n = n0 + wc * 64 + ct * 16 + l16;
    float bias = bp[n];
#pragma unroll
    for (int rt = 0; rt < 4; ++rt)
#pragma unroll
      for (int rr = 0; rr < 4; ++rr) {
        int m = m0 + wr * 64 + rt * 16 + l4 * 4 + rr;
        out[(size_t)m * Cn + n] = acc[rt][ct][rr] + bias;
      }
  }
}

// ---------------------------------------------------------------------------
// Fallback (ws too small): fused QKV + attention per (b,h). Known-good.
// ---------------------------------------------------------------------------
__global__ __launch_bounds__(256, 1)
void attn_fused(const float* __restrict__ x, const float* __restrict__ Wk,
                const float* __restrict__ Wq, const float* __restrict__ Wv,
                __bf16* __restrict__ att) {
  __shared__ __bf16 Ks[Tn * HSn];
  __shared__ __bf16 Vt[HSn * Tn];
  __shared__ __bf16 Pq[4][64 * 64];

  int p = blockIdx.x;
  int r = p & 7;
  int q2 = p >> 3;
  int slot = q2 / Hn;
  int h = q2 - slot * Hn;
  int b = r + 8 * slot;

  int tid = threadIdx.x;
  int w = tid >> 6;
  int l = tid & 63;
  int l16 = l & 15;
  int l4 = l >> 4;

  const float* xb = x + (size_t)b * Tn * Cn;
  int qr = w * 64;

  f32x4 aq[4][4], ak[4][4], av[4][4];
#pragma unroll
  for (int i = 0; i < 4; ++i)
#pragma unroll
    for (int j = 0; j < 4; ++j) {
      aq[i][j] = (f32x4){0.f, 0.f, 0.f, 0.f};
      ak[i][j] = (f32x4){0.f, 0.f, 0.f, 0.f};
      av[i][j] = (f32x4){0.f, 0.f, 0.f, 0.f};
    }

  for (int ct6 = 0; ct6 < 6; ++ct6) {
    int c0 = ct6 * 64;
    bf16x8 a[4][2];
#pragma unroll
    for (int rt = 0; rt < 4; ++rt)
#pragma unroll
      for (int kk = 0; kk < 2; ++kk)
        a[rt][kk] =
            load_cvt8(xb + (size_t)(qr + rt * 16 + l16) * Cn + c0 + kk * 32 + l4 * 8);

    auto doMat = [&](const float* W, f32x4 (&acc)[4][4]) {
#pragma unroll
      for (int ct = 0; ct < 4; ++ct)
#pragma unroll
        for (int kk = 0; kk < 2; ++kk) {
          bf16x8 bb = load_cvt8(W + (size_t)(h * 64 + ct * 16 + l16) * Cn + c0 +
                                kk * 32 + l4 * 8);
#pragma unroll
          for (int rt = 0; rt < 4; ++rt)
            acc[rt][ct] = __builtin_amdgcn_mfma_f32_16x16x32_bf16(
                a[rt][kk], bb, acc[rt][ct], 0, 0, 0);
        }
    };
    doMat(Wq, aq);
    doMat(Wk, ak);
    doMat(Wv, av);
  }

#pragma unroll
  for (int rt = 0; rt < 4; ++rt)
#pragma unroll
    for (int ct = 0; ct < 4; ++ct)
#pragma unroll
      for (int rr = 0; rr < 4; ++rr) {
        int trow = qr + rt * 16 + l4 * 4 + rr;
        int col = ct * 16 + l16;
        Ks[trow * HSn + swz(trow, col)] = (__bf16)ak[rt][ct][rr];
        Vt[col * Tn + swz(col, trow)] = (__bf16)av[rt][ct][rr];
        int lrow = rt * 16 + l4 * 4 + rr;
        Pq[w][lrow * 64 + swz(lrow, col)] = (__bf16)(aq[rt][ct][rr] * 0.125f);
      }
  __syncthreads();

  bf16x8 qa[4][2];
#pragma unroll
  for (int rt = 0; rt < 4; ++rt)
#pragma unroll
    for (int kk = 0; kk < 2; ++kk) {
      int row = rt * 16 + l16;
      qa[rt][kk] = *(const bf16x8*)&Pq[w][row * 64 + swz(row, kk * 32 + l4 * 8)];
    }

  const float LOG2E = 1.44269504088896f;
  f32x4 o[4][4];
  f32x4 m_[4], lsum[4];
#pragma unroll
  for (int i = 0; i < 4; ++i) {
#pragma unroll
    for (int j = 0; j < 4; ++j) o[i][j] = (f32x4){0.f, 0.f, 0.f, 0.f};
    m_[i] = (f32x4){-1e30f, -1e30f, -1e30f, -1e30f};
    lsum[i] = (f32x4){0.f, 0.f, 0.f, 0.f};
  }

  for (int jt = 0; jt <= w; ++jt) {
    f32x4 s[4][4];
#pragma unroll
    for (int i = 0; i < 4; ++i)
#pragma unroll
      for (int j = 0; j < 4; ++j) s[i][j] = (f32x4){0.f, 0.f, 0.f, 0.f};

#pragma unroll
    for (int kk = 0; kk < 2; ++kk)
#pragma unroll
      for (int ct = 0; ct < 4; ++ct) {
        int key = jt * 64 + ct * 16 + l16;
        bf16x8 kf = *(const bf16x8*)&Ks[key * HSn + swz(key, kk * 32 + l4 * 8)];
#pragma unroll
        for (int rt = 0; rt < 4; ++rt)
          s[rt][ct] = __builtin_amdgcn_mfma_f32_16x16x32_bf16(qa[rt][kk], kf,
                                                              s[rt][ct], 0, 0, 0);
      }

    if (jt == w) {
#pragma unroll
      for (int rt = 0; rt < 4; ++rt)
#pragma unroll
        for (int ct = 0; ct < 4; ++ct)
#pragma unroll
          for (int rr = 0; rr < 4; ++rr) {
            int ql = rt * 16 + l4 * 4 + rr;
            int kl = ct * 16 + l16;
            if (kl > ql) s[rt][ct][rr] = -1e30f;
          }
    }

#pragma unroll
    for (int rt = 0; rt < 4; ++rt) {
      float mt[4], corr[4], rsum[4];
#pragma unroll
      for (int rr = 0; rr < 4; ++rr)
        mt[rr] = fmaxf(fmaxf(s[rt][0][rr], s[rt][1][rr]),
                       fmaxf(s[rt][2][rr], s[rt][3][rr]));
#pragma unroll
      for (int off = 1; off < 16; off <<= 1)
#pragma unroll
        for (int rr = 0; rr < 4; ++rr)
          mt[rr] = fmaxf(mt[rr], __shfl_xor(mt[rr], off, 64));
#pragma unroll
      for (int rr = 0; rr < 4; ++rr) {
        float mnew = fmaxf(m_[rt][rr], mt[rr]);
        corr[rr] = exp2f((m_[rt][rr] - mnew) * LOG2E);
        m_[rt][rr] = mnew;
      }
#pragma unroll
      for (int ct = 0; ct < 4; ++ct)
#pragma unroll
        for (int rr = 0; rr < 4; ++rr)
          s[rt][ct][rr] = exp2f((s[rt][ct][rr] - m_[rt][rr]) * LOG2E);
#pragma unroll
      for (int rr = 0; rr < 4; ++rr)
        rsum[rr] = (s[rt][0][rr] + s[rt][1][rr]) + (s[rt][2][rr] + s[rt][3][rr]);
#pragma unroll
      for (int off = 1; off < 16; off <<= 1)
#pragma unroll
        for (int rr = 0; rr < 4; ++rr) rsum[rr] += __shfl_xor(rsum[rr], off, 64);
#pragma unroll
      for (int rr = 0; rr < 4; ++rr)
        lsum[rt][rr] = lsum[rt][rr] * corr[rr] + rsum[rr];
#pragma unroll
      for (int cd = 0; cd < 4; ++cd)
#pragma unroll
        for (int rr = 0; rr < 4; ++rr) o[rt][cd][rr] *= corr[rr];

#pragma unroll
      for (int ct = 0; ct < 4; ++ct)
#pragma unroll
        for (int rr = 0; rr < 4; ++rr) {
          int lr = rt * 16 + l4 * 4 + rr;
          Pq[w][lr * 64 + swz(lr, ct * 16 + l16)] = (__bf16)s[rt][ct][rr];
        }
    }

#pragma unroll
    for (int kk = 0; kk < 2; ++kk) {
      bf16x8 pa[4];
#pragma unroll
      for (int rt = 0; rt < 4; ++rt) {
        int row = rt * 16 + l16;
        pa[rt] = *(const bf16x8*)&Pq[w][row * 64 + swz(row, kk * 32 + l4 * 8)];
      }
#pragma unroll
      for (int cd = 0; cd < 4; ++cd) {
        int drow = cd * 16 + l16;
        bf16x8 vb =
            *(const bf16x8*)&Vt[drow * Tn + swz(drow, jt * 64 + kk * 32 + l4 * 8)];
#pragma unroll
        for (int rt = 0; rt < 4; ++rt)
          o[rt][cd] = __builtin_amdgcn_mfma_f32_16x16x32_bf16(pa[rt], vb,
                                                              o[rt][cd], 0, 0, 0);
      }
    }
  }

  __bf16* ab = att + (size_t)b * Tn * Cn + h * HSn;
#pragma unroll
  for (int rt = 0; rt < 4; ++rt)
#pragma unroll
    for (int cd = 0; cd < 4; ++cd)
#pragma unroll
      for (int rr = 0; rr < 4; ++rr) {
        int trow = qr + rt * 16 + l4 * 4 + rr;
        float val = o[rt][cd][rr] / lsum[rt][rr];
        ab[(size_t)trow * Cn + cd * 16 + l16] = (__bf16)val;
      }
}

extern "C" void kernel_launch(void* const* d_in, const int* in_sizes, int n_in,
                              void* d_out, int out_size, void* d_ws, size_t ws_size,
                              hipStream_t stream) {
  const float* x  = (const float*)d_in[0];
  const float* Wk = (const float*)d_in[1];
  const float* Wq = (const float*)d_in[2];
  const float* Wv = (const float*)d_in[3];
  const float* Wp = (const float*)d_in[4];
  const float* bp = (const float*)d_in[5];
  float* out = (float*)d_out;

  const size_t E2 = (size_t)Bn * Tn * Cn * 2;  // 50331648 bytes
  __bf16* att = (__bf16*)d_ws;                 // region 0: xb then att

  if (ws_size >= 4 * E2) {
    __bf16* xb = (__bf16*)d_ws;                        // region 0 (pre-attn)
    __bf16* qt_ = (__bf16*)((char*)d_ws + E2);
    __bf16* kt_ = (__bf16*)((char*)d_ws + 2 * E2);
    __bf16* vt_ = (__bf16*)((char*)d_ws + 3 * E2);
    cvt_x<<<3072, 256, 0, stream>>>(x, xb);
    qkv_gemm<<<4608, 256, 0, stream>>>(xb, Wq, Wk, Wv, qt_, kt_, vt_);
    attn4<<<1536, 256, 0, stream>>>(qt_, kt_, vt_, att);
  } else {
    attn_fused<<<Bn * Hn, 256, 0, stream>>>(x, Wk, Wq, Wv, att);
  }
  proj_kernel<<<512 * 3, 256, 0, stream>>>(att, Wp, bp, out);
}

// Round 5
// 316.446 us; speedup vs baseline: 1.5382x; 1.0037x over previous
//
#include <hip/hip_runtime.h>
#include <hip/hip_bf16.h>

#define Bn 256
#define Tn 256
#define Cn 384
#define Hn 6
#define HSn 64

typedef __attribute__((ext_vector_type(8))) __bf16 bf16x8;
typedef __attribute__((ext_vector_type(4))) float f32x4;

// XOR swizzle in ELEMENT units for bf16 LDS tiles with 128-elem rows.
__device__ __forceinline__ int swz(int row, int col) {
  return col ^ ((row & 7) << 3);
}

__device__ __forceinline__ bf16x8 load_cvt8(const float* src) {
  f32x4 f0 = *(const f32x4*)(src);
  f32x4 f1 = *(const f32x4*)(src + 4);
  bf16x8 t;
  t[0] = (__bf16)f0[0]; t[1] = (__bf16)f0[1];
  t[2] = (__bf16)f0[2]; t[3] = (__bf16)f0[3];
  t[4] = (__bf16)f1[0]; t[5] = (__bf16)f1[1];
  t[6] = (__bf16)f1[2]; t[7] = (__bf16)f1[3];
  return t;
}

// Fragment-order image layout: a 128x64 (rows x K) operand tile is stored as
// [kk 2][rt 8][lane 64][e 8] where element = (row = rt*16 + (l&15),
// col = kk*32 + ((l>>4)&3)*8 + e). Every fragment load is then ONE
// lane-contiguous 1KB global_load_dwordx4.

// ---------------------------------------------------------------------------
// K0a: W (3 matrices, f32) -> fragment-order bf16 image (in d_out scratch).
// Wimg idx = ((((mat*3+nt)*6+kt)*2+kk)*8+rt)*512 + l*8 + e.  Q pre-scaled.
// ---------------------------------------------------------------------------
__global__ __launch_bounds__(256, 4)
void cvt_w(const float* __restrict__ Wq, const float* __restrict__ Wk,
           const float* __restrict__ Wv, __bf16* __restrict__ Wimg) {
  int bb = blockIdx.x;              // 54 = 3 mats x 3 n-tiles x 6 k-tiles
  int mat = bb / 18;
  int nt = (bb / 6) % 3;
  int kt = bb % 6;
  const float* W = (mat == 0) ? Wq : (mat == 1) ? Wk : Wv;
  float scale = (mat == 0) ? 0.125f : 1.0f;
  int tid = threadIdx.x;
#pragma unroll
  for (int i = 0; i < 4; ++i) {
    int q = tid + 256 * i;          // 0..1023
    int row = q >> 3;               // n-local 0..127
    int c8 = (q & 7) * 8;           // k-local, 8-aligned
    const float* src = W + (size_t)(nt * 128 + row) * Cn + kt * 64 + c8;
    f32x4 f0 = *(const f32x4*)src;
    f32x4 f1 = *(const f32x4*)(src + 4);
    bf16x8 t;
    t[0] = (__bf16)(f0[0] * scale); t[1] = (__bf16)(f0[1] * scale);
    t[2] = (__bf16)(f0[2] * scale); t[3] = (__bf16)(f0[3] * scale);
    t[4] = (__bf16)(f1[0] * scale); t[5] = (__bf16)(f1[1] * scale);
    t[6] = (__bf16)(f1[2] * scale); t[7] = (__bf16)(f1[3] * scale);
    int rt = row >> 4, l16 = row & 15;
    int kk = c8 >> 5, l4 = (c8 >> 3) & 3;
    size_t idx = ((size_t)(((bb)*2 + kk) * 8 + rt)) * 512 + (l4 * 16 + l16) * 8;
    *(bf16x8*)&Wimg[idx] = t;
  }
}

// ---------------------------------------------------------------------------
// K0b: x (f32) -> fragment-order bf16 image xa: [bm 512][kt 6][kk][rt][l][e].
// ---------------------------------------------------------------------------
__global__ __launch_bounds__(256, 4)
void cvt_x(const float* __restrict__ x, __bf16* __restrict__ xa) {
  int tt = blockIdx.x;              // 3072 = 512 bm x 6 kt
  int bm = tt / 6, kt = tt % 6;
  int tid = threadIdx.x;
#pragma unroll
  for (int i = 0; i < 4; ++i) {
    int q = tid + 256 * i;
    int row = q >> 3;
    int c8 = (q & 7) * 8;
    bf16x8 v = load_cvt8(x + (size_t)(bm * 128 + row) * Cn + kt * 64 + c8);
    int rt = row >> 4, l16 = row & 15;
    int kk = c8 >> 5, l4 = (c8 >> 3) & 3;
    *(bf16x8*)&xa[(size_t)tt * 8192 + ((kk * 8 + rt) * 64 + l4 * 16 + l16) * 8] = v;
  }
}

// ---------------------------------------------------------------------------
// K1: QKV GEMM, barrier-free mainloop. All operands are direct fragment
// loads (1KB coalesced) from L2-resident images. Epilogue relayouts through
// LDS (only LDS/barriers in the kernel) into fragment-order Q/K/V images:
//   Qimg per (b,h): [st 8][rt2 2][kk 2][l][8]   (A-frag, 32-row stripes)
//   Kimg per (b,h): [jt 4][kk 2][ct 4][l][8]    (B-frag, keys)
//   Vimg per (b,h): [jt 4][kk 2][cd 4][l][8]    (B-frag, V^T: rows d, cols t)
// ---------------------------------------------------------------------------
__global__ __launch_bounds__(256, 2)
void qkv_gemm(const __bf16* __restrict__ xa, const __bf16* __restrict__ Wimg,
              __bf16* __restrict__ qimg, __bf16* __restrict__ kimg,
              __bf16* __restrict__ vimg) {
  __shared__ __bf16 Tr[128 * 128];   // 32 KB epilogue relayout

  int p = blockIdx.x;
  int wgid = (p & 7) * 576 + (p >> 3);   // bijective, 4608 % 8 == 0
  int bm = wgid / 9, bn = wgid % 9;      // bn: mat*3 + nt

  int tid = threadIdx.x;
  int l = tid & 63, wid = tid >> 6;
  int wr = wid >> 1, wc = wid & 1;
  int l16 = l & 15, l4 = l >> 4;

  const __bf16* Abase = xa + (size_t)bm * 6 * 8192;
  const __bf16* Bbase = Wimg + (size_t)bn * 6 * 8192;

  f32x4 acc[4][4];
#pragma unroll
  for (int i = 0; i < 4; ++i)
#pragma unroll
    for (int j = 0; j < 4; ++j) acc[i][j] = (f32x4){0.f, 0.f, 0.f, 0.f};

#pragma unroll 2
  for (int kt = 0; kt < 6; ++kt) {
#pragma unroll
    for (int kk = 0; kk < 2; ++kk) {
      bf16x8 a[4], bb[4];
#pragma unroll
      for (int rt = 0; rt < 4; ++rt)
        a[rt] = *(const bf16x8*)&Abase[(size_t)kt * 8192 +
                                       ((kk * 8 + wr * 4 + rt) * 64 + l) * 8];
#pragma unroll
      for (int ct = 0; ct < 4; ++ct)
        bb[ct] = *(const bf16x8*)&Bbase[(size_t)kt * 8192 +
                                        ((kk * 8 + wc * 4 + ct) * 64 + l) * 8];
#pragma unroll
      for (int rt = 0; rt < 4; ++rt)
#pragma unroll
        for (int ct = 0; ct < 4; ++ct)
          acc[rt][ct] = __builtin_amdgcn_mfma_f32_16x16x32_bf16(a[rt], bb[ct],
                                                                acc[rt][ct], 0, 0, 0);
    }
  }

  int b = bm >> 1;                   // 128 rows never cross a batch
  int halfsel = bm & 1;              // which 128-token half
  size_t bhbase = (size_t)b * Hn;    // + h

  if (bn < 6) {
    // ---- Q/K: Tr[t 128][n 128] then fragment-order 16B stores -----------
#pragma unroll
    for (int ct = 0; ct < 4; ++ct)
#pragma unroll
      for (int rt = 0; rt < 4; ++rt)
#pragma unroll
        for (int rr = 0; rr < 4; ++rr) {
          int tl = wr * 64 + rt * 16 + l4 * 4 + rr;
          int nl = wc * 64 + ct * 16 + l16;
          Tr[tl * 128 + (nl ^ ((tl & 7) << 3))] = (__bf16)acc[rt][ct][rr];
        }
    __syncthreads();
    if (bn < 3) {  // Q: A-frag image, 32-row stripes
      int nt = bn;
#pragma unroll
      for (int i = 0; i < 8; ++i) {
        int cid = i * 256 + tid;                 // [h2][st 4][rt2][kk][l]
        int ll = cid & 63;
        int kk = (cid >> 6) & 1;
        int rt2 = (cid >> 7) & 1;
        int st_loc = (cid >> 8) & 3;
        int h2 = cid >> 10;
        int tl = st_loc * 32 + rt2 * 16 + (ll & 15);
        int nl = h2 * 64 + kk * 32 + ((ll >> 4) & 3) * 8;
        bf16x8 v = *(const bf16x8*)&Tr[tl * 128 + (nl ^ ((tl & 7) << 3))];
        int h = nt * 2 + h2;
        int st = halfsel * 4 + st_loc;
        *(bf16x8*)&qimg[(((bhbase + h) * 8 + st) * 4 + rt2 * 2 + kk) * 512 +
                        ll * 8] = v;
      }
    } else {       // K: B-frag image, 64-key tiles
      int nt = bn - 3;
#pragma unroll
      for (int i = 0; i < 8; ++i) {
        int cid = i * 256 + tid;                 // [h2][jt 2][ct 4][kk][l]
        int ll = cid & 63;
        int kk = (cid >> 6) & 1;
        int ct = (cid >> 7) & 3;
        int jt_loc = (cid >> 9) & 1;
        int h2 = cid >> 10;
        int tl = jt_loc * 64 + ct * 16 + (ll & 15);
        int nl = h2 * 64 + kk * 32 + ((ll >> 4) & 3) * 8;
        bf16x8 v = *(const bf16x8*)&Tr[tl * 128 + (nl ^ ((tl & 7) << 3))];
        int h = nt * 2 + h2;
        int jt = halfsel * 2 + jt_loc;
        *(bf16x8*)&kimg[((((bhbase + h) * 4 + jt) * 2 + kk) * 4 + ct) * 512 +
                        ll * 8] = v;
      }
    }
  } else {
    // ---- V: Tr[d 128][t 128] (transposed) then fragment-order stores ----
#pragma unroll
    for (int ct = 0; ct < 4; ++ct)
#pragma unroll
      for (int rt = 0; rt < 4; ++rt)
#pragma unroll
        for (int rr = 0; rr < 4; ++rr) {
          int nl = wc * 64 + ct * 16 + l16;          // d (2 heads)
          int ml = wr * 64 + rt * 16 + l4 * 4 + rr;  // t-local
          Tr[nl * 128 + (ml ^ ((nl & 7) << 3))] = (__bf16)acc[rt][ct][rr];
        }
    __syncthreads();
    int nt = bn - 6;
#pragma unroll
    for (int i = 0; i < 8; ++i) {
      int cid = i * 256 + tid;                   // [h2][jt 2][kk][cd 4][l]
      int ll = cid & 63;
      int cd = (cid >> 6) & 3;
      int kk = (cid >> 8) & 1;
      int jt_loc = (cid >> 9) & 1;
      int h2 = cid >> 10;
      int nl = h2 * 64 + cd * 16 + (ll & 15);        // d-local
      int ml = jt_loc * 64 + kk * 32 + ((ll >> 4) & 3) * 8;  // t-local
      bf16x8 v = *(const bf16x8*)&Tr[nl * 128 + (ml ^ ((nl & 7) << 3))];
      int h = nt * 2 + h2;
      int jt = halfsel * 2 + jt_loc;
      *(bf16x8*)&vimg[((((bhbase + h) * 4 + jt) * 2 + kk) * 4 + cd) * 512 +
                      ll * 8] = v;
    }
  }
}

// ---------------------------------------------------------------------------
// K2: flash attention, barrier-free. One block per (b,h), 4 waves; wave w
// owns stripes {w, 7-w} (32 rows each) -> exactly 5 stripe-tiles per wave.
// Q/K/V fragments load directly from images (1KB coalesced, L2-resident).
// Only per-wave Pq LDS (no __syncthreads at all).
// ---------------------------------------------------------------------------
__global__ __launch_bounds__(256, 2)
void attn5(const __bf16* __restrict__ qimg, const __bf16* __restrict__ kimg,
           const __bf16* __restrict__ vimg, __bf16* __restrict__ att) {
  __shared__ __bf16 Pq[4][32 * 64];   // 16 KB

  int p = blockIdx.x;
  int wgid = (p & 7) * 192 + (p >> 3);   // 1536 blocks, bijective
  int b = wgid / 6;
  int h = wgid % 6;

  int tid = threadIdx.x, w = tid >> 6, l = tid & 63;
  int l16 = l & 15, l4 = l >> 4;

  size_t bh = (size_t)b * Hn + h;
  const __bf16* Qb = qimg + bh * 16384;
  const __bf16* Kb = kimg + bh * 16384;
  const __bf16* Vb = vimg + bh * 16384;

  int sA = w, sB = 7 - w;
  bf16x8 qa[2][2][2];                  // [stripe][rt2][kk]
#pragma unroll
  for (int si = 0; si < 2; ++si) {
    int s = si ? sB : sA;
#pragma unroll
    for (int rt = 0; rt < 2; ++rt)
#pragma unroll
      for (int kk = 0; kk < 2; ++kk)
        qa[si][rt][kk] = *(const bf16x8*)&Qb[((s * 2 + rt) * 2 + kk) * 512 + l * 8];
  }

  const float LOG2E = 1.44269504088896f;
  f32x4 o[2][2][4];
  f32x4 m_[2][2], lsum[2][2];
#pragma unroll
  for (int si = 0; si < 2; ++si)
#pragma unroll
    for (int rt = 0; rt < 2; ++rt) {
#pragma unroll
      for (int cd = 0; cd < 4; ++cd) o[si][rt][cd] = (f32x4){0.f, 0.f, 0.f, 0.f};
      m_[si][rt] = (f32x4){-1e30f, -1e30f, -1e30f, -1e30f};
      lsum[si][rt] = (f32x4){0.f, 0.f, 0.f, 0.f};
    }

  int ntw = ((7 - w) >> 1) + 1;        // wave's key-tile count (3 or 4)
  for (int jt = 0; jt < ntw; ++jt) {
    // K and V fragments for this key tile (shared by both stripes)
    bf16x8 kf[2][4], vf[2][4];
#pragma unroll
    for (int kk = 0; kk < 2; ++kk)
#pragma unroll
      for (int ct = 0; ct < 4; ++ct) {
        kf[kk][ct] = *(const bf16x8*)&Kb[((jt * 2 + kk) * 4 + ct) * 512 + l * 8];
        vf[kk][ct] = *(const bf16x8*)&Vb[((jt * 2 + kk) * 4 + ct) * 512 + l * 8];
      }

#pragma unroll
    for (int si = 0; si < 2; ++si) {
      int s = si ? sB : sA;
      if (jt > (s >> 1)) continue;     // causal

      f32x4 sv[2][4];
#pragma unroll
      for (int i = 0; i < 2; ++i)
#pragma unroll
        for (int j = 0; j < 4; ++j) sv[i][j] = (f32x4){0.f, 0.f, 0.f, 0.f};

#pragma unroll
      for (int kk = 0; kk < 2; ++kk)
#pragma unroll
        for (int ct = 0; ct < 4; ++ct)
#pragma unroll
          for (int rt = 0; rt < 2; ++rt)
            sv[rt][ct] = __builtin_amdgcn_mfma_f32_16x16x32_bf16(
                qa[si][rt][kk], kf[kk][ct], sv[rt][ct], 0, 0, 0);

      if (jt == (s >> 1)) {            // diagonal tile: causal mask
#pragma unroll
        for (int rt = 0; rt < 2; ++rt)
#pragma unroll
          for (int ct = 0; ct < 4; ++ct)
#pragma unroll
            for (int rr = 0; rr < 4; ++rr) {
              int ql = s * 32 + rt * 16 + l4 * 4 + rr;
              int kl = jt * 64 + ct * 16 + l16;
              if (kl > ql) sv[rt][ct][rr] = -1e30f;
            }
      }

#pragma unroll
      for (int rt = 0; rt < 2; ++rt) {
        float mt[4], corr[4], rsum[4];
#pragma unroll
        for (int rr = 0; rr < 4; ++rr)
          mt[rr] = fmaxf(fmaxf(sv[rt][0][rr], sv[rt][1][rr]),
                         fmaxf(sv[rt][2][rr], sv[rt][3][rr]));
#pragma unroll
        for (int off = 1; off < 16; off <<= 1)
#pragma unroll
          for (int rr = 0; rr < 4; ++rr)
            mt[rr] = fmaxf(mt[rr], __shfl_xor(mt[rr], off, 64));
#pragma unroll
        for (int rr = 0; rr < 4; ++rr) {
          float mnew = fmaxf(m_[si][rt][rr], mt[rr]);
          corr[rr] = exp2f((m_[si][rt][rr] - mnew) * LOG2E);
          m_[si][rt][rr] = mnew;
        }
#pragma unroll
        for (int ct = 0; ct < 4; ++ct)
#pragma unroll
          for (int rr = 0; rr < 4; ++rr)
            sv[rt][ct][rr] = exp2f((sv[rt][ct][rr] - m_[si][rt][rr]) * LOG2E);
#pragma unroll
        for (int rr = 0; rr < 4; ++rr)
          rsum[rr] = (sv[rt][0][rr] + sv[rt][1][rr]) + (sv[rt][2][rr] + sv[rt][3][rr]);
#pragma unroll
        for (int off = 1; off < 16; off <<= 1)
#pragma unroll
          for (int rr = 0; rr < 4; ++rr) rsum[rr] += __shfl_xor(rsum[rr], off, 64);
#pragma unroll
        for (int rr = 0; rr < 4; ++rr)
          lsum[si][rt][rr] = lsum[si][rt][rr] * corr[rr] + rsum[rr];
#pragma unroll
        for (int cd = 0; cd < 4; ++cd)
#pragma unroll
          for (int rr = 0; rr < 4; ++rr) o[si][rt][cd][rr] *= corr[rr];
#pragma unroll
        for (int ct = 0; ct < 4; ++ct)
#pragma unroll
          for (int rr = 0; rr < 4; ++rr) {
            int lr = rt * 16 + l4 * 4 + rr;
            Pq[w][lr * 64 + swz(lr, ct * 16 + l16)] = (__bf16)sv[rt][ct][rr];
          }
      }

#pragma unroll
      for (int kk = 0; kk < 2; ++kk) {
        bf16x8 pa[2];
#pragma unroll
        for (int rt = 0; rt < 2; ++rt) {
          int row = rt * 16 + l16;
          pa[rt] = *(const bf16x8*)&Pq[w][row * 64 + swz(row, kk * 32 + l4 * 8)];
        }
#pragma unroll
        for (int cd = 0; cd < 4; ++cd)
#pragma unroll
          for (int rt = 0; rt < 2; ++rt)
            o[si][rt][cd] = __builtin_amdgcn_mfma_f32_16x16x32_bf16(
                pa[rt], vf[kk][cd], o[si][rt][cd], 0, 0, 0);
      }
    }
  }

#pragma unroll
  for (int si = 0; si < 2; ++si) {
    int s = si ? sB : sA;
#pragma unroll
    for (int rt = 0; rt < 2; ++rt)
#pragma unroll
      for (int cd = 0; cd < 4; ++cd)
#pragma unroll
        for (int rr = 0; rr < 4; ++rr) {
          int t = s * 32 + rt * 16 + l4 * 4 + rr;
          float val = o[si][rt][cd][rr] / lsum[si][rt][rr];
          att[((size_t)b * Tn + t) * Cn + h * HSn + cd * 16 + l16] = (__bf16)val;
        }
  }
}

// ---------------------------------------------------------------------------
// K3: out = att @ Wp^T + bp   (M=65536, N=384, K=384), f32 output.
// ---------------------------------------------------------------------------
__global__ __launch_bounds__(256, 2)
void proj_kernel(const __bf16* __restrict__ att, const float* __restrict__ Wp,
                 const float* __restrict__ bp, float* __restrict__ out) {
  __shared__ __bf16 As[128 * 64];
  __shared__ __bf16 Bs[128 * 64];

  int bn = blockIdx.x / 512;
  int bm = blockIdx.x - bn * 512;
  int m0 = bm * 128, n0 = bn * 128;

  int tid = threadIdx.x;
  int l = tid & 63;
  int wid = tid >> 6;
  int wr = wid >> 1, wc = wid & 1;
  int l16 = l & 15, l4 = l >> 4;

  f32x4 acc[4][4];
#pragma unroll
  for (int i = 0; i < 4; ++i)
#pragma unroll
    for (int j = 0; j < 4; ++j) acc[i][j] = (f32x4){0.f, 0.f, 0.f, 0.f};

  for (int kt = 0; kt < 6; ++kt) {
    int k0 = kt * 64;
#pragma unroll
    for (int i = 0; i < 4; ++i) {
      int chunk = tid + 256 * i;
      int row = chunk >> 3;
      int c8 = (chunk & 7) * 8;
      bf16x8 v = *(const bf16x8*)&att[(size_t)(m0 + row) * Cn + k0 + c8];
      *(bf16x8*)&As[row * 64 + (c8 ^ ((row & 7) << 3))] = v;
    }
#pragma unroll
    for (int i = 0; i < 4; ++i) {
      int chunk = tid + 256 * i;
      int row = chunk >> 3;
      int c8 = (chunk & 7) * 8;
      bf16x8 t = load_cvt8(Wp + (size_t)(n0 + row) * Cn + k0 + c8);
      *(bf16x8*)&Bs[row * 64 + (c8 ^ ((row & 7) << 3))] = t;
    }
    __syncthreads();
#pragma unroll
    for (int kk = 0; kk < 2; ++kk) {
      bf16x8 a[4], bb[4];
#pragma unroll
      for (int rt = 0; rt < 4; ++rt) {
        int row = wr * 64 + rt * 16 + l16;
        a[rt] = *(const bf16x8*)&As[row * 64 + ((kk * 32 + l4 * 8) ^ ((row & 7) << 3))];
      }
#pragma unroll
      for (int ct = 0; ct < 4; ++ct) {
        int row = wc * 64 + ct * 16 + l16;
        bb[ct] = *(const bf16x8*)&Bs[row * 64 + ((kk * 32 + l4 * 8) ^ ((row & 7) << 3))];
      }
#pragma unroll
      for (int rt = 0; rt < 4; ++rt)
#pragma unroll
        for (int ct = 0; ct < 4; ++ct)
          acc[rt][ct] = __builtin_amdgcn_mfma_f32_16x16x32_bf16(a[rt], bb[ct],
                                                                acc[rt][ct], 0, 0, 0);
    }
    __syncthreads();
  }

#pragma unroll
  for (int ct = 0; ct < 4; ++ct) {
    int n = n0 + wc * 64 + ct * 16 + l16;
    float bias = bp[n];
#pragma unroll
    for (int rt = 0; rt < 4; ++rt)
#pragma unroll
      for (int rr = 0; rr < 4; ++rr) {
        int m = m0 + wr * 64 + rt * 16 + l4 * 4 + rr;
        out[(size_t)m * Cn + n] = acc[rt][ct][rr] + bias;
      }
  }
}

// ---------------------------------------------------------------------------
// Fallback (ws too small): fused QKV + attention per (b,h). Known-good.
// ---------------------------------------------------------------------------
__global__ __launch_bounds__(256, 1)
void attn_fused(const float* __restrict__ x, const float* __restrict__ Wk,
                const float* __restrict__ Wq, const float* __restrict__ Wv,
                __bf16* __restrict__ att) {
  __shared__ __bf16 Ks[Tn * HSn];
  __shared__ __bf16 Vt[HSn * Tn];
  __shared__ __bf16 Pq[4][64 * 64];

  int p = blockIdx.x;
  int r = p & 7;
  int q2 = p >> 3;
  int slot = q2 / Hn;
  int h = q2 - slot * Hn;
  int b = r + 8 * slot;

  int tid = threadIdx.x;
  int w = tid >> 6;
  int l = tid & 63;
  int l16 = l & 15;
  int l4 = l >> 4;

  const float* xb = x + (size_t)b * Tn * Cn;
  int qr = w * 64;

  f32x4 aq[4][4], ak[4][4], av[4][4];
#pragma unroll
  for (int i = 0; i < 4; ++i)
#pragma unroll
    for (int j = 0; j < 4; ++j) {
      aq[i][j] = (f32x4){0.f, 0.f, 0.f, 0.f};
      ak[i][j] = (f32x4){0.f, 0.f, 0.f, 0.f};
      av[i][j] = (f32x4){0.f, 0.f, 0.f, 0.f};
    }

  for (int ct6 = 0; ct6 < 6; ++ct6) {
    int c0 = ct6 * 64;
    bf16x8 a[4][2];
#pragma unroll
    for (int rt = 0; rt < 4; ++rt)
#pragma unroll
      for (int kk = 0; kk < 2; ++kk)
        a[rt][kk] =
            load_cvt8(xb + (size_t)(qr + rt * 16 + l16) * Cn + c0 + kk * 32 + l4 * 8);

    auto doMat = [&](const float* W, f32x4 (&acc)[4][4]) {
#pragma unroll
      for (int ct = 0; ct < 4; ++ct)
#pragma unroll
        for (int kk = 0; kk < 2; ++kk) {
          bf16x8 bb = load_cvt8(W + (size_t)(h * 64 + ct * 16 + l16) * Cn + c0 +
                                kk * 32 + l4 * 8);
#pragma unroll
          for (int rt = 0; rt < 4; ++rt)
            acc[rt][ct] = __builtin_amdgcn_mfma_f32_16x16x32_bf16(
                a[rt][kk], bb, acc[rt][ct], 0, 0, 0);
        }
    };
    doMat(Wq, aq);
    doMat(Wk, ak);
    doMat(Wv, av);
  }

#pragma unroll
  for (int rt = 0; rt < 4; ++rt)
#pragma unroll
    for (int ct = 0; ct < 4; ++ct)
#pragma unroll
      for (int rr = 0; rr < 4; ++rr) {
        int trow = qr + rt * 16 + l4 * 4 + rr;
        int col = ct * 16 + l16;
        Ks[trow * HSn + swz(trow, col)] = (__bf16)ak[rt][ct][rr];
        Vt[col * Tn + swz(col, trow)] = (__bf16)av[rt][ct][rr];
        int lrow = rt * 16 + l4 * 4 + rr;
        Pq[w][lrow * 64 + swz(lrow, col)] = (__bf16)(aq[rt][ct][rr] * 0.125f);
      }
  __syncthreads();

  bf16x8 qa[4][2];
#pragma unroll
  for (int rt = 0; rt < 4; ++rt)
#pragma unroll
    for (int kk = 0; kk < 2; ++kk) {
      int row = rt * 16 + l16;
      qa[rt][kk] = *(const bf16x8*)&Pq[w][row * 64 + swz(row, kk * 32 + l4 * 8)];
    }

  const float LOG2E = 1.44269504088896f;
  f32x4 o[4][4];
  f32x4 m_[4], lsum[4];
#pragma unroll
  for (int i = 0; i < 4; ++i) {
#pragma unroll
    for (int j = 0; j < 4; ++j) o[i][j] = (f32x4){0.f, 0.f, 0.f, 0.f};
    m_[i] = (f32x4){-1e30f, -1e30f, -1e30f, -1e30f};
    lsum[i] = (f32x4){0.f, 0.f, 0.f, 0.f};
  }

  for (int jt = 0; jt <= w; ++jt) {
    f32x4 s[4][4];
#pragma unroll
    for (int i = 0; i < 4; ++i)
#pragma unroll
      for (int j = 0; j < 4; ++j) s[i][j] = (f32x4){0.f, 0.f, 0.f, 0.f};

#pragma unroll
    for (int kk = 0; kk < 2; ++kk)
#pragma unroll
      for (int ct = 0; ct < 4; ++ct) {
        int key = jt * 64 + ct * 16 + l16;
        bf16x8 kf = *(const bf16x8*)&Ks[key * HSn + swz(key, kk * 32 + l4 * 8)];
#pragma unroll
        for (int rt = 0; rt < 4; ++rt)
          s[rt][ct] = __builtin_amdgcn_mfma_f32_16x16x32_bf16(qa[rt][kk], kf,
                                                              s[rt][ct], 0, 0, 0);
      }

    if (jt == w) {
#pragma unroll
      for (int rt = 0; rt < 4; ++rt)
#pragma unroll
        for (int ct = 0; ct < 4; ++ct)
#pragma unroll
          for (int rr = 0; rr < 4; ++rr) {
            int ql = rt * 16 + l4 * 4 + rr;
            int kl = ct * 16 + l16;
            if (kl > ql) s[rt][ct][rr] = -1e30f;
          }
    }

#pragma unroll
    for (int rt = 0; rt < 4; ++rt) {
      float mt[4], corr[4], rsum[4];
#pragma unroll
      for (int rr = 0; rr < 4; ++rr)
        mt[rr] = fmaxf(fmaxf(s[rt][0][rr], s[rt][1][rr]),
                       fmaxf(s[rt][2][rr], s[rt][3][rr]));
#pragma unroll
      for (int off = 1; off < 16; off <<= 1)
#pragma unroll
        for (int rr = 0; rr < 4; ++rr)
          mt[rr] = fmaxf(mt[rr], __shfl_xor(mt[rr], off, 64));
#pragma unroll
      for (int rr = 0; rr < 4; ++rr) {
        float mnew = fmaxf(m_[rt][rr], mt[rr]);
        corr[rr] = exp2f((m_[rt][rr] - mnew) * LOG2E);
        m_[rt][rr] = mnew;
      }
#pragma unroll
      for (int ct = 0; ct < 4; ++ct)
#pragma unroll
        for (int rr = 0; rr < 4; ++rr)
          s[rt][ct][rr] = exp2f((s[rt][ct][rr] - m_[rt][rr]) * LOG2E);
#pragma unroll
      for (int rr = 0; rr < 4; ++rr)
        rsum[rr] = (s[rt][0][rr] + s[rt][1][rr]) + (s[rt][2][rr] + s[rt][3][rr]);
#pragma unroll
      for (int off = 1; off < 16; off <<= 1)
#pragma unroll
        for (int rr = 0; rr < 4; ++rr) rsum[rr] += __shfl_xor(rsum[rr], off, 64);
#pragma unroll
      for (int rr = 0; rr < 4; ++rr)
        lsum[rt][rr] = lsum[rt][rr] * corr[rr] + rsum[rr];
#pragma unroll
      for (int cd = 0; cd < 4; ++cd)
#pragma unroll
        for (int rr = 0; rr < 4; ++rr) o[rt][cd][rr] *= corr[rr];

#pragma unroll
      for (int ct = 0; ct < 4; ++ct)
#pragma unroll
        for (int rr = 0; rr < 4; ++rr) {
          int lr = rt * 16 + l4 * 4 + rr;
          Pq[w][lr * 64 + swz(lr, ct * 16 + l16)] = (__bf16)s[rt][ct][rr];
        }
    }

#pragma unroll
    for (int kk = 0; kk < 2; ++kk) {
      bf16x8 pa[4];
#pragma unroll
      for (int rt = 0; rt < 4; ++rt) {
        int row = rt * 16 + l16;
        pa[rt] = *(const bf16x8*)&Pq[w][row * 64 + swz(row, kk * 32 + l4 * 8)];
      }
#pragma unroll
      for (int cd = 0; cd < 4; ++cd) {
        int drow = cd * 16 + l16;
        bf16x8 vb =
            *(const bf16x8*)&Vt[drow * Tn + swz(drow, jt * 64 + kk * 32 + l4 * 8)];
#pragma unroll
        for (int rt = 0; rt < 4; ++rt)
          o[rt][cd] = __builtin_amdgcn_mfma_f32_16x16x32_bf16(pa[rt], vb,
                                                              o[rt][cd], 0, 0, 0);
      }
    }
  }

  __bf16* ab = att + (size_t)b * Tn * Cn + h * HSn;
#pragma unroll
  for (int rt = 0; rt < 4; ++rt)
#pragma unroll
    for (int cd = 0; cd < 4; ++cd)
#pragma unroll
      for (int rr = 0; rr < 4; ++rr) {
        int trow = qr + rt * 16 + l4 * 4 + rr;
        float val = o[rt][cd][rr] / lsum[rt][rr];
        ab[(size_t)trow * Cn + cd * 16 + l16] = (__bf16)val;
      }
}

extern "C" void kernel_launch(void* const* d_in, const int* in_sizes, int n_in,
                              void* d_out, int out_size, void* d_ws, size_t ws_size,
                              hipStream_t stream) {
  const float* x  = (const float*)d_in[0];
  const float* Wk = (const float*)d_in[1];
  const float* Wq = (const float*)d_in[2];
  const float* Wv = (const float*)d_in[3];
  const float* Wp = (const float*)d_in[4];
  const float* bp = (const float*)d_in[5];
  float* out = (float*)d_out;

  const size_t E2 = (size_t)Bn * Tn * Cn * 2;  // 50331648 bytes
  __bf16* att = (__bf16*)d_ws;                 // region 0: xa then att

  if (ws_size >= 4 * E2) {
    __bf16* xa   = (__bf16*)d_ws;                      // region 0 (pre-attn)
    __bf16* qimg = (__bf16*)((char*)d_ws + E2);
    __bf16* kimg = (__bf16*)((char*)d_ws + 2 * E2);
    __bf16* vimg = (__bf16*)((char*)d_ws + 3 * E2);
    __bf16* Wimg = (__bf16*)d_out;   // 1.7 MB scratch in out; proj overwrites
    cvt_w<<<54, 256, 0, stream>>>(Wq, Wk, Wv, Wimg);
    cvt_x<<<3072, 256, 0, stream>>>(x, xa);
    qkv_gemm<<<4608, 256, 0, stream>>>(xa, Wimg, qimg, kimg, vimg);
    attn5<<<1536, 256, 0, stream>>>(qimg, kimg, vimg, att);
  } else {
    attn_fused<<<Bn * Hn, 256, 0, stream>>>(x, Wk, Wq, Wv, att);
  }
  proj_kernel<<<512 * 3, 256, 0, stream>>>(att, Wp, bp, out);
}

// Round 7
// 291.930 us; speedup vs baseline: 1.6673x; 1.0840x over previous
//
#include <hip/hip_runtime.h>
#include <hip/hip_bf16.h>

#define Bn 256
#define Tn 256
#define Cn 384
#define Hn 6
#define HSn 64

typedef __attribute__((ext_vector_type(8))) __bf16 bf16x8;
typedef __attribute__((ext_vector_type(4))) float f32x4;

// XOR swizzle in ELEMENT units; valid for rows whose stride is a multiple
// of 64 elems (128B). Only touches bits 3..5 of the column index.
__device__ __forceinline__ int swz(int row, int col) {
  return col ^ ((row & 7) << 3);
}

__device__ __forceinline__ bf16x8 load_cvt8(const float* src) {
  f32x4 f0 = *(const f32x4*)(src);
  f32x4 f1 = *(const f32x4*)(src + 4);
  bf16x8 t;
  t[0] = (__bf16)f0[0]; t[1] = (__bf16)f0[1];
  t[2] = (__bf16)f0[2]; t[3] = (__bf16)f0[3];
  t[4] = (__bf16)f1[0]; t[5] = (__bf16)f1[1];
  t[6] = (__bf16)f1[2]; t[7] = (__bf16)f1[3];
  return t;
}

// ---------------------------------------------------------------------------
// K0: x (f32, 65536x384) -> xa (bf16, row-major, same shape). Pure stream.
// ---------------------------------------------------------------------------
__global__ __launch_bounds__(256, 4)
void cvt_x(const float* __restrict__ x, __bf16* __restrict__ xa) {
  int tid = threadIdx.x;
#pragma unroll
  for (int i = 0; i < 4; ++i) {
    size_t pos = (size_t)blockIdx.x * 8192 + ((size_t)tid + 256 * i) * 8;
    *(bf16x8*)&xa[pos] = load_cvt8(x + pos);
  }
}

// ---------------------------------------------------------------------------
// K1: QKV GEMM — proj_kernel clone. M=65536, N=1152 (9 bn of 128), K=384.
// bn-major grid. A: row-major bf16 xa staged to LDS (16B loads). B: f32 W
// staged with cvt (Q pre-scaled 0.125). Epilogue: 128x128 LDS transpose ->
// contiguous 16B stores of row-major Q/K [b,h,t,d] and V^T [b,h,d,t].
// ---------------------------------------------------------------------------
__global__ __launch_bounds__(256, 2)
void qkv3(const __bf16* __restrict__ xa, const float* __restrict__ Wq,
          const float* __restrict__ Wk, const float* __restrict__ Wv,
          __bf16* __restrict__ qr_, __bf16* __restrict__ kr_,
          __bf16* __restrict__ vr_) {
  __shared__ __bf16 smem[128 * 128];   // 32 KB: As | Bs, reused as Tr
  __bf16* As = smem;
  __bf16* Bs = smem + 8192;

  int bn = blockIdx.x / 512;           // bn-major like proj
  int bm = blockIdx.x - bn * 512;
  int mat = bn / 3, nt = bn % 3;
  const float* W = (mat == 0) ? Wq : (mat == 1) ? Wk : Wv;
  float scale = (mat == 0) ? 0.125f : 1.0f;
  int m0 = bm * 128, wrow0 = nt * 128;

  int tid = threadIdx.x;
  int l = tid & 63;
  int wid = tid >> 6;
  int wr = wid >> 1, wc = wid & 1;
  int l16 = l & 15, l4 = l >> 4;

  f32x4 acc[4][4];
#pragma unroll
  for (int i = 0; i < 4; ++i)
#pragma unroll
    for (int j = 0; j < 4; ++j) acc[i][j] = (f32x4){0.f, 0.f, 0.f, 0.f};

  for (int kt = 0; kt < 6; ++kt) {
    int k0 = kt * 64;
#pragma unroll
    for (int i = 0; i < 4; ++i) {
      int chunk = tid + 256 * i;
      int row = chunk >> 3;
      int c8 = (chunk & 7) * 8;
      *(bf16x8*)&As[row * 64 + swz(row, c8)] =
          *(const bf16x8*)&xa[(size_t)(m0 + row) * Cn + k0 + c8];
    }
#pragma unroll
    for (int i = 0; i < 4; ++i) {
      int chunk = tid + 256 * i;
      int row = chunk >> 3;
      int c8 = (chunk & 7) * 8;
      f32x4 f0 = *(const f32x4*)(W + (size_t)(wrow0 + row) * Cn + k0 + c8);
      f32x4 f1 = *(const f32x4*)(W + (size_t)(wrow0 + row) * Cn + k0 + c8 + 4);
      bf16x8 t;
      t[0] = (__bf16)(f0[0] * scale); t[1] = (__bf16)(f0[1] * scale);
      t[2] = (__bf16)(f0[2] * scale); t[3] = (__bf16)(f0[3] * scale);
      t[4] = (__bf16)(f1[0] * scale); t[5] = (__bf16)(f1[1] * scale);
      t[6] = (__bf16)(f1[2] * scale); t[7] = (__bf16)(f1[3] * scale);
      *(bf16x8*)&Bs[row * 64 + swz(row, c8)] = t;
    }
    __syncthreads();
#pragma unroll
    for (int kk = 0; kk < 2; ++kk) {
      bf16x8 a[4], bb[4];
#pragma unroll
      for (int rt = 0; rt < 4; ++rt) {
        int row = wr * 64 + rt * 16 + l16;
        a[rt] = *(const bf16x8*)&As[row * 64 + swz(row, kk * 32 + l4 * 8)];
      }
#pragma unroll
      for (int ct = 0; ct < 4; ++ct) {
        int row = wc * 64 + ct * 16 + l16;
        bb[ct] = *(const bf16x8*)&Bs[row * 64 + swz(row, kk * 32 + l4 * 8)];
      }
#pragma unroll
      for (int rt = 0; rt < 4; ++rt)
#pragma unroll
        for (int ct = 0; ct < 4; ++ct)
          acc[rt][ct] = __builtin_amdgcn_mfma_f32_16x16x32_bf16(a[rt], bb[ct],
                                                                acc[rt][ct], 0, 0, 0);
    }
    __syncthreads();
  }

  int b = bm >> 1;                 // 128-row tiles never cross a batch
  int t0 = (bm & 1) * 128;
  __bf16* Tr = smem;               // 128x128 relayout (after last barrier)

  if (mat < 2) {
    // ---- Q/K: Tr[t][n], then contiguous row stores [b,h,t,d] ------------
#pragma unroll
    for (int ct = 0; ct < 4; ++ct)
#pragma unroll
      for (int rt = 0; rt < 4; ++rt)
#pragma unroll
        for (int rr = 0; rr < 4; ++rr) {
          int tl = wr * 64 + rt * 16 + l4 * 4 + rr;
          int nl = wc * 64 + ct * 16 + l16;
          Tr[tl * 128 + (nl ^ ((tl & 7) << 3))] = (__bf16)acc[rt][ct][rr];
        }
    __syncthreads();
    __bf16* ob = (mat == 0) ? qr_ : kr_;
#pragma unroll
    for (int i = 0; i < 8; ++i) {
      int gid = i * 256 + tid;         // 2048 chunk-stores of 16B
      int h2 = gid >> 10;              // n half (head within pair)
      int rl = (gid >> 3) & 127;       // t-local
      int c8 = gid & 7;                // d chunk
      bf16x8 v = *(const bf16x8*)&Tr[rl * 128 +
                                     ((h2 * 64 + c8 * 8) ^ ((rl & 7) << 3))];
      int h = nt * 2 + h2;
      *(bf16x8*)&ob[(((size_t)b * Hn + h) * Tn + t0 + rl) * HSn + c8 * 8] = v;
    }
  } else {
    // ---- V: Tr[d][t] (transposed), then row stores [b,h,d,t] ------------
#pragma unroll
    for (int ct = 0; ct < 4; ++ct)
#pragma unroll
      for (int rt = 0; rt < 4; ++rt)
#pragma unroll
        for (int rr = 0; rr < 4; ++rr) {
          int nl = wc * 64 + ct * 16 + l16;          // d over 2 heads
          int ml = wr * 64 + rt * 16 + l4 * 4 + rr;  // t-local 0..127
          Tr[nl * 128 + (ml ^ ((nl & 7) << 3))] = (__bf16)acc[rt][ct][rr];
        }
    __syncthreads();
    // FIX(r6): full tile is 128 nl x 16 t-chunks = 2048 chunks (was 1024,
    // leaving t-local 64..127 unwritten -> poison in half of V).
#pragma unroll
    for (int i = 0; i < 8; ++i) {
      int gid = i * 256 + tid;         // 2048 chunk-stores of 16B
      int nl = gid >> 4;               // d-local over 2 heads (0..127)
      int tc = gid & 15;               // t chunk within 128-half (0..15)
      bf16x8 v = *(const bf16x8*)&Tr[nl * 128 +
                                     ((tc * 8) ^ ((nl & 7) << 3))];
      int h = nt * 2 + (nl >> 6), d = nl & 63;
      *(bf16x8*)&vr_[(((size_t)b * Hn + h) * HSn + d) * Tn + t0 + tc * 8] = v;
    }
  }
}

// ---------------------------------------------------------------------------
// K2: flash attention. One block per (b,h); stage K [256][64] + V^T [64][256]
// into swizzled LDS once (single barrier), then pure per-wave flash: wave w
// owns stripes {w, 7-w} (32 rows) -> exactly 5 causal stripe-tiles each.
// Output relayout through per-wave Pq -> 128B-contiguous row stores.
// ---------------------------------------------------------------------------
__global__ __launch_bounds__(256, 2)
void attn6(const __bf16* __restrict__ qr_, const __bf16* __restrict__ kr_,
           const __bf16* __restrict__ vr_, __bf16* __restrict__ att) {
  __shared__ __bf16 Ks[256 * 64];     // 32 KB
  __shared__ __bf16 Vt[64 * 256];     // 32 KB
  __shared__ __bf16 Pq[4][32 * 64];   // 16 KB

  int bh = blockIdx.x;                // plain order; no cross-block reuse
  int b = bh / 6, h = bh % 6;

  int tid = threadIdx.x, w = tid >> 6, l = tid & 63;
  int l16 = l & 15, l4 = l >> 4;

  const __bf16* Qr = qr_ + (size_t)bh * Tn * HSn;
  const __bf16* Kr = kr_ + (size_t)bh * Tn * HSn;
  const __bf16* Vr = vr_ + (size_t)bh * HSn * Tn;

  // ---- stage K and V^T (64 KB total, 16B/lane synchronous) ---------------
#pragma unroll
  for (int i = 0; i < 8; ++i) {
    int chunk = tid + 256 * i;        // 2048 chunks of 8 elems
    int row = chunk >> 3;             // key 0..255
    int c8 = (chunk & 7) * 8;         // d
    *(bf16x8*)&Ks[row * 64 + swz(row, c8)] = *(const bf16x8*)&Kr[chunk * 8];
  }
#pragma unroll
  for (int i = 0; i < 8; ++i) {
    int chunk = tid + 256 * i;
    int d = chunk >> 5;               // 0..63
    int tc = (chunk & 31) * 8;        // t col
    *(bf16x8*)&Vt[d * 256 + swz(d, tc)] = *(const bf16x8*)&Vr[chunk * 8];
  }

  // Q fragments (direct, 64B segments, once)
  int sA = w, sB = 7 - w;
  bf16x8 qa[2][2][2];
#pragma unroll
  for (int si = 0; si < 2; ++si) {
    int s = si ? sB : sA;
#pragma unroll
    for (int rt = 0; rt < 2; ++rt)
#pragma unroll
      for (int kk = 0; kk < 2; ++kk)
        qa[si][rt][kk] = *(const bf16x8*)&Qr[(size_t)(s * 32 + rt * 16 + l16) *
                                                 HSn + kk * 32 + l4 * 8];
  }
  __syncthreads();   // staging complete; no further barriers

  const float LOG2E = 1.44269504088896f;
  f32x4 o[2][2][4];
  f32x4 m_[2][2], lsum[2][2];
#pragma unroll
  for (int si = 0; si < 2; ++si)
#pragma unroll
    for (int rt = 0; rt < 2; ++rt) {
#pragma unroll
      for (int cd = 0; cd < 4; ++cd) o[si][rt][cd] = (f32x4){0.f, 0.f, 0.f, 0.f};
      m_[si][rt] = (f32x4){-1e30f, -1e30f, -1e30f, -1e30f};
      lsum[si][rt] = (f32x4){0.f, 0.f, 0.f, 0.f};
    }

#pragma unroll
  for (int si = 0; si < 2; ++si) {
    int s = si ? sB : sA;
    int ntile = (s >> 1) + 1;
    for (int jt = 0; jt < ntile; ++jt) {
      f32x4 sv[2][4];
#pragma unroll
      for (int i = 0; i < 2; ++i)
#pragma unroll
        for (int j = 0; j < 4; ++j) sv[i][j] = (f32x4){0.f, 0.f, 0.f, 0.f};

#pragma unroll
      for (int kk = 0; kk < 2; ++kk)
#pragma unroll
        for (int ct = 0; ct < 4; ++ct) {
          int key = jt * 64 + ct * 16 + l16;
          bf16x8 kf = *(const bf16x8*)&Ks[key * 64 + swz(key, kk * 32 + l4 * 8)];
#pragma unroll
          for (int rt = 0; rt < 2; ++rt)
            sv[rt][ct] = __builtin_amdgcn_mfma_f32_16x16x32_bf16(
                qa[si][rt][kk], kf, sv[rt][ct], 0, 0, 0);
        }

      if (jt == (s >> 1)) {           // diagonal tile: causal mask
#pragma unroll
        for (int rt = 0; rt < 2; ++rt)
#pragma unroll
          for (int ct = 0; ct < 4; ++ct)
#pragma unroll
            for (int rr = 0; rr < 4; ++rr) {
              int ql = s * 32 + rt * 16 + l4 * 4 + rr;
              int kl = jt * 64 + ct * 16 + l16;
              if (kl > ql) sv[rt][ct][rr] = -1e30f;
            }
      }

#pragma unroll
      for (int rt = 0; rt < 2; ++rt) {
        float mt[4], corr[4], rsum[4];
#pragma unroll
        for (int rr = 0; rr < 4; ++rr)
          mt[rr] = fmaxf(fmaxf(sv[rt][0][rr], sv[rt][1][rr]),
                         fmaxf(sv[rt][2][rr], sv[rt][3][rr]));
#pragma unroll
        for (int off = 1; off < 16; off <<= 1)
#pragma unroll
          for (int rr = 0; rr < 4; ++rr)
            mt[rr] = fmaxf(mt[rr], __shfl_xor(mt[rr], off, 64));
#pragma unroll
        for (int rr = 0; rr < 4; ++rr) {
          float mnew = fmaxf(m_[si][rt][rr], mt[rr]);
          corr[rr] = exp2f((m_[si][rt][rr] - mnew) * LOG2E);
          m_[si][rt][rr] = mnew;
        }
#pragma unroll
        for (int ct = 0; ct < 4; ++ct)
#pragma unroll
          for (int rr = 0; rr < 4; ++rr)
            sv[rt][ct][rr] = exp2f((sv[rt][ct][rr] - m_[si][rt][rr]) * LOG2E);
#pragma unroll
        for (int rr = 0; rr < 4; ++rr)
          rsum[rr] = (sv[rt][0][rr] + sv[rt][1][rr]) +
                     (sv[rt][2][rr] + sv[rt][3][rr]);
#pragma unroll
        for (int off = 1; off < 16; off <<= 1)
#pragma unroll
          for (int rr = 0; rr < 4; ++rr) rsum[rr] += __shfl_xor(rsum[rr], off, 64);
#pragma unroll
        for (int rr = 0; rr < 4; ++rr)
          lsum[si][rt][rr] = lsum[si][rt][rr] * corr[rr] + rsum[rr];
#pragma unroll
        for (int cd = 0; cd < 4; ++cd)
#pragma unroll
          for (int rr = 0; rr < 4; ++rr) o[si][rt][cd][rr] *= corr[rr];
#pragma unroll
        for (int ct = 0; ct < 4; ++ct)
#pragma unroll
          for (int rr = 0; rr < 4; ++rr) {
            int lr = rt * 16 + l4 * 4 + rr;
            Pq[w][lr * 64 + swz(lr, ct * 16 + l16)] = (__bf16)sv[rt][ct][rr];
          }
      }

#pragma unroll
      for (int kk = 0; kk < 2; ++kk) {
        bf16x8 pa[2];
#pragma unroll
        for (int rt = 0; rt < 2; ++rt) {
          int row = rt * 16 + l16;
          pa[rt] = *(const bf16x8*)&Pq[w][row * 64 + swz(row, kk * 32 + l4 * 8)];
        }
#pragma unroll
        for (int cd = 0; cd < 4; ++cd) {
          int drow = cd * 16 + l16;
          bf16x8 vf = *(const bf16x8*)&Vt[drow * 256 +
                                          swz(drow, jt * 64 + kk * 32 + l4 * 8)];
#pragma unroll
          for (int rt = 0; rt < 2; ++rt)
            o[si][rt][cd] = __builtin_amdgcn_mfma_f32_16x16x32_bf16(
                pa[rt], vf, o[si][rt][cd], 0, 0, 0);
        }
      }
    }
  }

  // ---- epilogue: per stripe, relayout O through Pq, 128B row stores ------
#pragma unroll
  for (int si = 0; si < 2; ++si) {
    int s = si ? sB : sA;
#pragma unroll
    for (int rt = 0; rt < 2; ++rt)
#pragma unroll
      for (int cd = 0; cd < 4; ++cd)
#pragma unroll
        for (int rr = 0; rr < 4; ++rr) {
          int lr = rt * 16 + l4 * 4 + rr;
          Pq[w][lr * 64 + swz(lr, cd * 16 + l16)] =
              (__bf16)(o[si][rt][cd][rr] / lsum[si][rt][rr]);
        }
#pragma unroll
    for (int pp = 0; pp < 4; ++pp) {
      int r = pp * 8 + (l >> 3);
      int c8 = (l & 7) * 8;
      bf16x8 v = *(const bf16x8*)&Pq[w][r * 64 + swz(r, c8)];
      int t = s * 32 + r;
      *(bf16x8*)&att[((size_t)b * Tn + t) * Cn + h * HSn + c8] = v;
    }
  }
}

// ---------------------------------------------------------------------------
// K3: out = att @ Wp^T + bp   (M=65536, N=384, K=384), f32 output. Unchanged.
// ---------------------------------------------------------------------------
__global__ __launch_bounds__(256, 2)
void proj_kernel(const __bf16* __restrict__ att, const float* __restrict__ Wp,
                 const float* __restrict__ bp, float* __restrict__ out) {
  __shared__ __bf16 As[128 * 64];
  __shared__ __bf16 Bs[128 * 64];

  int bn = blockIdx.x / 512;
  int bm = blockIdx.x - bn * 512;
  int m0 = bm * 128, n0 = bn * 128;

  int tid = threadIdx.x;
  int l = tid & 63;
  int wid = tid >> 6;
  int wr = wid >> 1, wc = wid & 1;
  int l16 = l & 15, l4 = l >> 4;

  f32x4 acc[4][4];
#pragma unroll
  for (int i = 0; i < 4; ++i)
#pragma unroll
    for (int j = 0; j < 4; ++j) acc[i][j] = (f32x4){0.f, 0.f, 0.f, 0.f};

  for (int kt = 0; kt < 6; ++kt) {
    int k0 = kt * 64;
#pragma unroll
    for (int i = 0; i < 4; ++i) {
      int chunk = tid + 256 * i;
      int row = chunk >> 3;
      int c8 = (chunk & 7) * 8;
      bf16x8 v = *(const bf16x8*)&att[(size_t)(m0 + row) * Cn + k0 + c8];
      *(bf16x8*)&As[row * 64 + swz(row, c8)] = v;
    }
#pragma unroll
    for (int i = 0; i < 4; ++i) {
      int chunk = tid + 256 * i;
      int row = chunk >> 3;
      int c8 = (chunk & 7) * 8;
      bf16x8 t = load_cvt8(Wp + (size_t)(n0 + row) * Cn + k0 + c8);
      *(bf16x8*)&Bs[row * 64 + swz(row, c8)] = t;
    }
    __syncthreads();
#pragma unroll
    for (int kk = 0; kk < 2; ++kk) {
      bf16x8 a[4], bb[4];
#pragma unroll
      for (int rt = 0; rt < 4; ++rt) {
        int row = wr * 64 + rt * 16 + l16;
        a[rt] = *(const bf16x8*)&As[row * 64 + swz(row, kk * 32 + l4 * 8)];
      }
#pragma unroll
      for (int ct = 0; ct < 4; ++ct) {
        int row = wc * 64 + ct * 16 + l16;
        bb[ct] = *(const bf16x8*)&Bs[row * 64 + swz(row, kk * 32 + l4 * 8)];
      }
#pragma unroll
      for (int rt = 0; rt < 4; ++rt)
#pragma unroll
        for (int ct = 0; ct < 4; ++ct)
          acc[rt][ct] = __builtin_amdgcn_mfma_f32_16x16x32_bf16(a[rt], bb[ct],
                                                                acc[rt][ct], 0, 0, 0);
    }
    __syncthreads();
  }

#pragma unroll
  for (int ct = 0; ct < 4; ++ct) {
    int n = n0 + wc * 64 + ct * 16 + l16;
    float bias = bp[n];
#pragma unroll
    for (int rt = 0; rt < 4; ++rt)
#pragma unroll
      for (int rr = 0; rr < 4; ++rr) {
        int m = m0 + wr * 64 + rt * 16 + l4 * 4 + rr;
        out[(size_t)m * Cn + n] = acc[rt][ct][rr] + bias;
      }
  }
}

// ---------------------------------------------------------------------------
// Fallback (ws too small): fused QKV + attention per (b,h). Known-good.
// ---------------------------------------------------------------------------
__global__ __launch_bounds__(256, 1)
void attn_fused(const float* __restrict__ x, const float* __restrict__ Wk,
                const float* __restrict__ Wq, const float* __restrict__ Wv,
                __bf16* __restrict__ att) {
  __shared__ __bf16 Ks[Tn * HSn];
  __shared__ __bf16 Vt[HSn * Tn];
  __shared__ __bf16 Pq[4][64 * 64];

  int p = blockIdx.x;
  int r = p & 7;
  int q2 = p >> 3;
  int slot = q2 / Hn;
  int h = q2 - slot * Hn;
  int b = r + 8 * slot;

  int tid = threadIdx.x;
  int w = tid >> 6;
  int l = tid & 63;
  int l16 = l & 15;
  int l4 = l >> 4;

  const float* xb = x + (size_t)b * Tn * Cn;
  int qr = w * 64;

  f32x4 aq[4][4], ak[4][4], av[4][4];
#pragma unroll
  for (int i = 0; i < 4; ++i)
#pragma unroll
    for (int j = 0; j < 4; ++j) {
      aq[i][j] = (f32x4){0.f, 0.f, 0.f, 0.f};
      ak[i][j] = (f32x4){0.f, 0.f, 0.f, 0.f};
      av[i][j] = (f32x4){0.f, 0.f, 0.f, 0.f};
    }

  for (int ct6 = 0; ct6 < 6; ++ct6) {
    int c0 = ct6 * 64;
    bf16x8 a[4][2];
#pragma unroll
    for (int rt = 0; rt < 4; ++rt)
#pragma unroll
      for (int kk = 0; kk < 2; ++kk)
        a[rt][kk] =
            load_cvt8(xb + (size_t)(qr + rt * 16 + l16) * Cn + c0 + kk * 32 + l4 * 8);

    auto doMat = [&](const float* W, f32x4 (&acc)[4][4]) {
#pragma unroll
      for (int ct = 0; ct < 4; ++ct)
#pragma unroll
        for (int kk = 0; kk < 2; ++kk) {
          bf16x8 bb = load_cvt8(W + (size_t)(h * 64 + ct * 16 + l16) * Cn + c0 +
                                kk * 32 + l4 * 8);
#pragma unroll
          for (int rt = 0; rt < 4; ++rt)
            acc[rt][ct] = __builtin_amdgcn_mfma_f32_16x16x32_bf16(
                a[rt][kk], bb, acc[rt][ct], 0, 0, 0);
        }
    };
    doMat(Wq, aq);
    doMat(Wk, ak);
    doMat(Wv, av);
  }

#pragma unroll
  for (int rt = 0; rt < 4; ++rt)
#pragma unroll
    for (int ct = 0; ct < 4; ++ct)
#pragma unroll
      for (int rr = 0; rr < 4; ++rr) {
        int trow = qr + rt * 16 + l4 * 4 + rr;
        int col = ct * 16 + l16;
        Ks[trow * HSn + swz(trow, col)] = (__bf16)ak[rt][ct][rr];
        Vt[col * Tn + swz(col, trow)] = (__bf16)av[rt][ct][rr];
        int lrow = rt * 16 + l4 * 4 + rr;
        Pq[w][lrow * 64 + swz(lrow, col)] = (__bf16)(aq[rt][ct][rr] * 0.125f);
      }
  __syncthreads();

  bf16x8 qa[4][2];
#pragma unroll
  for (int rt = 0; rt < 4; ++rt)
#pragma unroll
    for (int kk = 0; kk < 2; ++kk) {
      int row = rt * 16 + l16;
      qa[rt][kk] = *(const bf16x8*)&Pq[w][row * 64 + swz(row, kk * 32 + l4 * 8)];
    }

  const float LOG2E = 1.44269504088896f;
  f32x4 o[4][4];
  f32x4 m_[4], lsum[4];
#pragma unroll
  for (int i = 0; i < 4; ++i) {
#pragma unroll
    for (int j = 0; j < 4; ++j) o[i][j] = (f32x4){0.f, 0.f, 0.f, 0.f};
    m_[i] = (f32x4){-1e30f, -1e30f, -1e30f, -1e30f};
    lsum[i] = (f32x4){0.f, 0.f, 0.f, 0.f};
  }

  for (int jt = 0; jt <= w; ++jt) {
    f32x4 s[4][4];
#pragma unroll
    for (int i = 0; i < 4; ++i)
#pragma unroll
      for (int j = 0; j < 4; ++j) s[i][j] = (f32x4){0.f, 0.f, 0.f, 0.f};

#pragma unroll
    for (int kk = 0; kk < 2; ++kk)
#pragma unroll
      for (int ct = 0; ct < 4; ++ct) {
        int key = jt * 64 + ct * 16 + l16;
        bf16x8 kf = *(const bf16x8*)&Ks[key * HSn + swz(key, kk * 32 + l4 * 8)];
#pragma unroll
        for (int rt = 0; rt < 4; ++rt)
          s[rt][ct] = __builtin_amdgcn_mfma_f32_16x16x32_bf16(qa[rt][kk], kf,
                                                              s[rt][ct], 0, 0, 0);
      }

    if (jt == w) {
#pragma unroll
      for (int rt = 0; rt < 4; ++rt)
#pragma unroll
        for (int ct = 0; ct < 4; ++ct)
#pragma unroll
          for (int rr = 0; rr < 4; ++rr) {
            int ql = rt * 16 + l4 * 4 + rr;
            int kl = ct * 16 + l16;
            if (kl > ql) s[rt][ct][rr] = -1e30f;
          }
    }

#pragma unroll
    for (int rt = 0; rt < 4; ++rt) {
      float mt[4], corr[4], rsum[4];
#pragma unroll
      for (int rr = 0; rr < 4; ++rr)
        mt[rr] = fmaxf(fmaxf(s[rt][0][rr], s[rt][1][rr]),
                       fmaxf(s[rt][2][rr], s[rt][3][rr]));
#pragma unroll
      for (int off = 1; off < 16; off <<= 1)
#pragma unroll
        for (int rr = 0; rr < 4; ++rr)
          mt[rr] = fmaxf(mt[rr], __shfl_xor(mt[rr], off, 64));
#pragma unroll
      for (int rr = 0; rr < 4; ++rr) {
        float mnew = fmaxf(m_[rt][rr], mt[rr]);
        corr[rr] = exp2f((m_[rt][rr] - mnew) * LOG2E);
        m_[rt][rr] = mnew;
      }
#pragma unroll
      for (int ct = 0; ct < 4; ++ct)
#pragma unroll
        for (int rr = 0; rr < 4; ++rr)
          s[rt][ct][rr] = exp2f((s[rt][ct][rr] - m_[rt][rr]) * LOG2E);
#pragma unroll
      for (int rr = 0; rr < 4; ++rr)
        rsum[rr] = (s[rt][0][rr] + s[rt][1][rr]) + (s[rt][2][rr] + s[rt][3][rr]);
#pragma unroll
      for (int off = 1; off < 16; off <<= 1)
#pragma unroll
        for (int rr = 0; rr < 4; ++rr) rsum[rr] += __shfl_xor(rsum[rr], off, 64);
#pragma unroll
      for (int rr = 0; rr < 4; ++rr)
        lsum[rt][rr] = lsum[rt][rr] * corr[rr] + rsum[rr];
#pragma unroll
      for (int cd = 0; cd < 4; ++cd)
#pragma unroll
        for (int rr = 0; rr < 4; ++rr) o[rt][cd][rr] *= corr[rr];

#pragma unroll
      for (int ct = 0; ct < 4; ++ct)
#pragma unroll
        for (int rr = 0; rr < 4; ++rr) {
          int lr = rt * 16 + l4 * 4 + rr;
          Pq[w][lr * 64 + swz(lr, ct * 16 + l16)] = (__bf16)s[rt][ct][rr];
        }
    }

#pragma unroll
    for (int kk = 0; kk < 2; ++kk) {
      bf16x8 pa[4];
#pragma unroll
      for (int rt = 0; rt < 4; ++rt) {
        int row = rt * 16 + l16;
        pa[rt] = *(const bf16x8*)&Pq[w][row * 64 + swz(row, kk * 32 + l4 * 8)];
      }
#pragma unroll
      for (int cd = 0; cd < 4; ++cd) {
        int drow = cd * 16 + l16;
        bf16x8 vb =
            *(const bf16x8*)&Vt[drow * Tn + swz(drow, jt * 64 + kk * 32 + l4 * 8)];
#pragma unroll
        for (int rt = 0; rt < 4; ++rt)
          o[rt][cd] = __builtin_amdgcn_mfma_f32_16x16x32_bf16(pa[rt], vb,
                                                              o[rt][cd], 0, 0, 0);
      }
    }
  }

  __bf16* ab = att + (size_t)b * Tn * Cn + h * HSn;
#pragma unroll
  for (int rt = 0; rt < 4; ++rt)
#pragma unroll
    for (int cd = 0; cd < 4; ++cd)
#pragma unroll
      for (int rr = 0; rr < 4; ++rr) {
        int trow = qr + rt * 16 + l4 * 4 + rr;
        float val = o[rt][cd][rr] / lsum[rt][rr];
        ab[(size_t)trow * Cn + cd * 16 + l16] = (__bf16)val;
      }
}

extern "C" void kernel_launch(void* const* d_in, const int* in_sizes, int n_in,
                              void* d_out, int out_size, void* d_ws, size_t ws_size,
                              hipStream_t stream) {
  const float* x  = (const float*)d_in[0];
  const float* Wk = (const float*)d_in[1];
  const float* Wq = (const float*)d_in[2];
  const float* Wv = (const float*)d_in[3];
  const float* Wp = (const float*)d_in[4];
  const float* bp = (const float*)d_in[5];
  float* out = (float*)d_out;

  const size_t E2 = (size_t)Bn * Tn * Cn * 2;  // 50331648 bytes
  __bf16* att = (__bf16*)d_ws;                 // region 0: xa then att

  if (ws_size >= 4 * E2) {
    __bf16* xa = (__bf16*)d_ws;                        // region 0 (pre-attn)
    __bf16* qb = (__bf16*)((char*)d_ws + E2);
    __bf16* kb = (__bf16*)((char*)d_ws + 2 * E2);
    __bf16* vb = (__bf16*)((char*)d_ws + 3 * E2);
    cvt_x<<<3072, 256, 0, stream>>>(x, xa);
    qkv3<<<4608, 256, 0, stream>>>(xa, Wq, Wk, Wv, qb, kb, vb);
    attn6<<<1536, 256, 0, stream>>>(qb, kb, vb, att);
  } else {
    attn_fused<<<Bn * Hn, 256, 0, stream>>>(x, Wk, Wq, Wv, att);
  }
  proj_kernel<<<512 * 3, 256, 0, stream>>>(att, Wp, bp, out);
}